// Round 4
// baseline (1352.523 us; speedup 1.0000x reference)
//
#include <hip/hip_runtime.h>
#include <math.h>

// Res_Slim_ViT_Adaptive — r9: wtrans write-coalescing fix.
// r8's mega-transpose had 2x HBM write amplification (WRITE 162MB for 81MB of
// bf16): 32x32 tiles wrote 64B row-segments (2B/lane x 32 lanes), partial-line.
// r9 re-tiles to 64k x 32n: LDS [64][33] stage, each thread packs 8 bf16 into a
// uint4 -> every output row is one full 128B aligned segment (8 lanes x 16B).
// Shapes: P=16 D=1024 NH=16 HD=64 MAG=4 B=2 V=4 H=256 W=512 L=512 KEEP=128 DEPTH=6

#define UNIT 1048576L   // 1M elements

typedef __attribute__((ext_vector_type(8))) short short8;
typedef __attribute__((ext_vector_type(4))) float f32x4;

#define GLDS(gp, lp) __builtin_amdgcn_global_load_lds( \
    (const __attribute__((address_space(1))) void*)(gp), \
    (__attribute__((address_space(3))) void*)(lp), 16, 0, 0)

__device__ __forceinline__ float gelu_f(float v){
  return 0.5f*v*(1.0f + erff(v*0.70710678118654752440f));
}

__device__ __forceinline__ unsigned short f2bf(float f){
  union { float f; unsigned u; } a; a.f = f;
  unsigned r = a.u + 0x7fffu + ((a.u >> 16) & 1u);
  return (unsigned short)(r >> 16);
}
__device__ __forceinline__ float bf2f(unsigned short u){
  union { unsigned u; float f; } a; a.u = (unsigned)u << 16;
  return a.f;
}

// =============== mega transpose-convert: W fp32 [K][N] -> Wt bf16 [N][K] ==============
// 64k x 32n tiles; reads 2x128B rows/wave, writes full 128B segments (uint4/thread).
struct WJobs {
  const float* W[10];
  unsigned short* T[10];
  int K[10], N[10];
  int start[10];
};

__global__ __launch_bounds__(256)
void wtrans_multi(WJobs J)
{
  __shared__ float tile[64][33];
  int bx = blockIdx.x;
  int j = 0;
  #pragma unroll
  for (int i = 1; i < 10; ++i) if (bx >= J.start[i]) j = i;
  int local = bx - J.start[j];
  int K = J.K[j], N = J.N[j];
  int nx = N >> 5, tpb = (K >> 6) * nx;
  int bz = local / tpb, rem = local % tpb;
  int k0 = (rem / nx) * 64, n0 = (rem % nx) * 32;
  const float* Wp = J.W[j] + (long)bz * K * N;
  unsigned short* Wo = J.T[j] + (long)bz * K * N;
  int tx = threadIdx.x & 31, ty = threadIdx.x >> 5;   // 32 x 8
  #pragma unroll
  for (int i = 0; i < 8; ++i)
    tile[ty*8+i][tx] = Wp[(long)(k0 + ty*8 + i)*N + n0 + tx];
  __syncthreads();
  int n = threadIdx.x >> 3, c = threadIdx.x & 7;   // out row n (0..31), 16B chunk c
  unsigned pk[4];
  #pragma unroll
  for (int q = 0; q < 4; ++q){
    unsigned lo = f2bf(tile[c*8 + 2*q][n]);
    unsigned hi = f2bf(tile[c*8 + 2*q + 1][n]);
    pk[q] = lo | (hi << 16);
  }
  uint4 v = {pk[0], pk[1], pk[2], pk[3]};
  *(uint4*)&Wo[(long)(n0 + n)*K + k0 + c*8] = v;
}

// =============== bf16 MFMA GEMM with optional split-K partial output ==================
// A: bf16 [M][K]; Wt: bf16 [N][K]. Tile TM x 128, BK=32, 256 threads.
template<int TM>
__global__ __launch_bounds__(256)
void gemm_bt(const unsigned short* __restrict__ A, const unsigned short* __restrict__ Wt,
             const float* __restrict__ bias, const float* __restrict__ res,
             float* __restrict__ Cf, unsigned short* __restrict__ Cb,
             float* __restrict__ Cp, long MN, int splits,
             int M, int N, int K, int ldc,
             long sA, long sW, long sBias, long sRes, long sC,
             int wmod, int act)
{
  constexpr int NJ = (TM == 128) ? 4 : 2;
  int bz0 = blockIdx.z;
  int sp = bz0 % splits, bz = bz0 / splits;
  A += (long)bz * sA;
  int wb = bz % wmod;
  Wt += (long)wb * sW;
  const float* bptr = bias ? bias + (long)wb * sBias : nullptr;
  const float* rptr = res  ? res  + (long)bz * sRes : nullptr;
  if (Cf) Cf += (long)bz * sC;
  if (Cb) Cb += (long)bz * sC;

  __shared__ __align__(16) unsigned short As[TM*32];
  __shared__ __align__(16) unsigned short Bs[128*32];

  int t = threadIdx.x;
  int wave = t >> 6, lane = t & 63;
  int ln = lane & 15, kg = lane >> 4;
  int wm, wn;
  if (TM == 128){ wm = (wave & 1) * 64; wn = (wave >> 1) * 64; }
  else          { wm = 0;               wn = wave * 32; }
  int row0 = blockIdx.y * TM, col0 = blockIdx.x * 128;

  f32x4 acc[4][NJ];
  f32x4 z = {0.f, 0.f, 0.f, 0.f};
  #pragma unroll
  for (int i = 0; i < 4; ++i)
    #pragma unroll
    for (int j = 0; j < NJ; ++j) acc[i][j] = z;

  int sm = t >> 2;          // 0..63
  int sk = (t & 3) * 8;     // halfword offset
  unsigned short* AsB = As + wave*512;
  unsigned short* BsB = Bs + wave*512;

  int kpb = K / splits;
  int kbeg = sp * kpb, kend = kbeg + kpb;
  for (int k0 = kbeg; k0 < kend; k0 += 32){
    if (TM == 128){
      GLDS(&A[(long)(row0 + sm)*K + k0 + sk],      AsB);
      GLDS(&A[(long)(row0 + 64 + sm)*K + k0 + sk], AsB + 2048);
    } else {
      GLDS(&A[(long)(row0 + sm)*K + k0 + sk],      AsB);
    }
    GLDS(&Wt[(long)(col0 + sm)*K + k0 + sk],      BsB);
    GLDS(&Wt[(long)(col0 + 64 + sm)*K + k0 + sk], BsB + 2048);
    __syncthreads();
    short8 af[4], bfg[NJ];
    #pragma unroll
    for (int i = 0; i < 4; ++i)  af[i]  = *(const short8*)&As[(wm + i*16 + ln)*32 + kg*8];
    #pragma unroll
    for (int j = 0; j < NJ; ++j) bfg[j] = *(const short8*)&Bs[(wn + j*16 + ln)*32 + kg*8];
    #pragma unroll
    for (int i = 0; i < 4; ++i)
      #pragma unroll
      for (int j = 0; j < NJ; ++j)
        acc[i][j] = __builtin_amdgcn_mfma_f32_16x16x32_bf16(af[i], bfg[j], acc[i][j], 0, 0, 0);
    __syncthreads();
  }

  // C/D layout: col = lane&15, row = (lane>>4)*4 + reg
  if (Cp){
    long nbat = gridDim.z / splits;
    float* P = Cp + ((long)sp*nbat + bz)*MN;
    #pragma unroll
    for (int i = 0; i < 4; ++i){
      int rbase = row0 + wm + i*16 + kg*4;
      #pragma unroll
      for (int j = 0; j < NJ; ++j){
        int c = col0 + wn + j*16 + ln;
        #pragma unroll
        for (int rr2 = 0; rr2 < 4; ++rr2)
          P[(long)(rbase + rr2)*ldc + c] = acc[i][j][rr2];
      }
    }
    return;
  }
  #pragma unroll
  for (int i = 0; i < 4; ++i){
    int rbase = row0 + wm + i*16 + kg*4;
    #pragma unroll
    for (int j = 0; j < NJ; ++j){
      int c = col0 + wn + j*16 + ln;
      float bv = bptr ? bptr[c] : 0.f;
      #pragma unroll
      for (int rr2 = 0; rr2 < 4; ++rr2){
        int rrow = rbase + rr2;
        float v = acc[i][j][rr2] + bv;
        if (rptr) v += rptr[(long)rrow*ldc + c];
        if (act == 1) v = gelu_f(v);
        if (Cf) Cf[(long)rrow*ldc + c] = v;
        if (Cb) Cb[(long)rrow*ldc + c] = f2bf(v);
      }
    }
  }
}

// ---------------- split-K epilogue reduce: sum partials + bias + res + act ------------
// sidx: optional scatter of output rows (N must be 1024): out row = bt*512 + sidx[...]
__global__ __launch_bounds__(256)
void reduce_ep(const float* __restrict__ Cp, int splits, int nbat, long MN, int N,
               const float* __restrict__ bias, const float* __restrict__ res, long sRes,
               float* __restrict__ Cf, unsigned short* __restrict__ Cb, long sC, int act,
               const int* __restrict__ sidx)
{
  long e4 = (long)blockIdx.x*256 + threadIdx.x;
  if (e4 >= (long)nbat*MN/4) return;
  long e = e4 * 4;
  int b = (int)(e / MN); long r = e % MN; int col = (int)(r % N);
  float4 s = *(const float4*)&Cp[(long)b*MN + r];
  for (int sp = 1; sp < splits; ++sp){
    float4 p = *(const float4*)&Cp[((long)sp*nbat + b)*MN + r];
    s.x += p.x; s.y += p.y; s.z += p.z; s.w += p.w;
  }
  if (bias){
    float4 bv = *(const float4*)&bias[col];
    s.x += bv.x; s.y += bv.y; s.z += bv.z; s.w += bv.w;
  }
  if (res){
    float4 rv = *(const float4*)&res[(long)b*sRes + r];
    s.x += rv.x; s.y += rv.y; s.z += rv.z; s.w += rv.w;
  }
  if (act == 1){
    s.x = gelu_f(s.x); s.y = gelu_f(s.y); s.z = gelu_f(s.z); s.w = gelu_f(s.w);
  }
  if (Cf){
    if (sidx){
      int rw = (int)(r >> 10); int bt = rw >> 7, ii = rw & 127;
      long orow = (long)bt*512 + sidx[bt*128 + ii];
      *(float4*)&Cf[orow*1024 + (r & 1023)] = s;
    } else {
      *(float4*)&Cf[(long)b*sC + r] = s;
    }
  }
  if (Cb){
    unsigned q0 = (unsigned)f2bf(s.x) | ((unsigned)f2bf(s.y) << 16);
    unsigned q1 = (unsigned)f2bf(s.z) | ((unsigned)f2bf(s.w) << 16);
    uint2 pk = {q0, q1};
    *(uint2*)&Cb[(long)b*sC + r] = pk;
  }
}

// ---------------- fused split-K reduce + bias + residual + LayerNorm ------------------
// N fixed = 1024. One row per block. Writes fp32 residual stream + bf16 LN output.
__global__ __launch_bounds__(256)
void reduce_ln(const float* __restrict__ Cp, int splits, int nbat, long MN,
               const float* __restrict__ bias,
               const float* __restrict__ res, long sRes,
               float* __restrict__ cur,
               const float* __restrict__ g, const float* __restrict__ b,
               unsigned short* __restrict__ hn)
{
  int row = blockIdx.x;
  int t = threadIdx.x;
  int rpb = (int)(MN >> 10);
  int bb = row / rpb;
  long r = (long)(row - bb*rpb)*1024 + t*4;
  float4 s = *(const float4*)&Cp[(long)bb*MN + r];
  for (int sp = 1; sp < splits; ++sp){
    float4 p = *(const float4*)&Cp[((long)sp*nbat + bb)*MN + r];
    s.x += p.x; s.y += p.y; s.z += p.z; s.w += p.w;
  }
  int col = t*4;
  float4 bv = *(const float4*)&bias[col];
  s.x += bv.x; s.y += bv.y; s.z += bv.z; s.w += bv.w;
  float4 rv = *(const float4*)&res[(long)bb*sRes + r];
  s.x += rv.x; s.y += rv.y; s.z += rv.z; s.w += rv.w;
  *(float4*)&cur[(long)row*1024 + col] = s;
  float sm = s.x + s.y + s.z + s.w;
  float ss = s.x*s.x + s.y*s.y + s.z*s.z + s.w*s.w;
  #pragma unroll
  for (int o = 32; o; o >>= 1){ sm += __shfl_xor(sm, o); ss += __shfl_xor(ss, o); }
  __shared__ float sa[4], sb[4];
  int w = t >> 6, lane = t & 63;
  if (!lane){ sa[w] = sm; sb[w] = ss; }
  __syncthreads();
  sm = sa[0] + sa[1] + sa[2] + sa[3];
  ss = sb[0] + sb[1] + sb[2] + sb[3];
  float mean = sm * (1.0f/1024.0f);
  float var  = ss * (1.0f/1024.0f) - mean*mean;
  float rstd = rsqrtf(var + 1e-5f);
  float4 gv = ((const float4*)g)[t];
  float4 bv2 = ((const float4*)b)[t];
  float ox = (s.x-mean)*rstd*gv.x + bv2.x;
  float oy = (s.y-mean)*rstd*gv.y + bv2.y;
  float oz = (s.z-mean)*rstd*gv.z + bv2.z;
  float ow = (s.w-mean)*rstd*gv.w + bv2.w;
  unsigned q0 = (unsigned)f2bf(ox) | ((unsigned)f2bf(oy) << 16);
  unsigned q1 = (unsigned)f2bf(oz) | ((unsigned)f2bf(ow) << 16);
  uint2 pk = {q0, q1};
  *(uint2*)&hn[(long)row*1024 + col] = pk;
}

// ---------------- LayerNorm over D=1024 -> bf16 out, one row per block ----------------
__global__ __launch_bounds__(256)
void ln_bf(const float* __restrict__ x, const float* __restrict__ g,
           const float* __restrict__ b, unsigned short* __restrict__ y)
{
  long r = blockIdx.x;
  int t = threadIdx.x;
  float4 v = ((const float4*)(x + r*1024))[t];
  float s  = v.x + v.y + v.z + v.w;
  float ss = v.x*v.x + v.y*v.y + v.z*v.z + v.w*v.w;
  #pragma unroll
  for (int o = 32; o; o >>= 1){ s += __shfl_xor(s, o); ss += __shfl_xor(ss, o); }
  __shared__ float sa[4], sb[4];
  int w = t >> 6, lane = t & 63;
  if (!lane){ sa[w] = s; sb[w] = ss; }
  __syncthreads();
  s  = sa[0] + sa[1] + sa[2] + sa[3];
  ss = sb[0] + sb[1] + sb[2] + sb[3];
  float mean = s * (1.0f/1024.0f);
  float var  = ss * (1.0f/1024.0f) - mean*mean;
  float rstd = rsqrtf(var + 1e-5f);
  float4 gv = ((const float4*)g)[t];
  float4 bv = ((const float4*)b)[t];
  float ox = (v.x-mean)*rstd*gv.x + bv.x;
  float oy = (v.y-mean)*rstd*gv.y + bv.y;
  float oz = (v.z-mean)*rstd*gv.z + bv.z;
  float ow = (v.w-mean)*rstd*gv.w + bv.w;
  unsigned q0 = (unsigned)f2bf(ox) | ((unsigned)f2bf(oy) << 16);
  unsigned q1 = (unsigned)f2bf(oz) | ((unsigned)f2bf(ow) << 16);
  uint2 pk = {q0, q1};
  *(uint2*)&y[r*1024 + t*4] = pk;
}

// ---------------- gather hard rows + LayerNorm ----------------------------------------
__global__ __launch_bounds__(256)
void gather_ln(const float* __restrict__ src, const int* __restrict__ idx,
               float* __restrict__ dst, const float* __restrict__ g,
               const float* __restrict__ b, unsigned short* __restrict__ hn)
{
  int r = blockIdx.x, t = threadIdx.x;
  int bb = r >> 7, i = r & 127;
  int s0 = idx[bb*128 + i];
  float4 v = ((const float4*)(src + ((long)bb*512 + s0)*1024))[t];
  ((float4*)(dst + (long)r*1024))[t] = v;
  float s  = v.x + v.y + v.z + v.w;
  float ss = v.x*v.x + v.y*v.y + v.z*v.z + v.w*v.w;
  #pragma unroll
  for (int o = 32; o; o >>= 1){ s += __shfl_xor(s, o); ss += __shfl_xor(ss, o); }
  __shared__ float sa[4], sb[4];
  int w = t >> 6, lane = t & 63;
  if (!lane){ sa[w] = s; sb[w] = ss; }
  __syncthreads();
  s  = sa[0] + sa[1] + sa[2] + sa[3];
  ss = sb[0] + sb[1] + sb[2] + sb[3];
  float mean = s * (1.0f/1024.0f);
  float var  = ss * (1.0f/1024.0f) - mean*mean;
  float rstd = rsqrtf(var + 1e-5f);
  float4 gv = ((const float4*)g)[t];
  float4 bv = ((const float4*)b)[t];
  float ox = (v.x-mean)*rstd*gv.x + bv.x;
  float oy = (v.y-mean)*rstd*gv.y + bv.y;
  float oz = (v.z-mean)*rstd*gv.z + bv.z;
  float ow = (v.w-mean)*rstd*gv.w + bv.w;
  unsigned q0 = (unsigned)f2bf(ox) | ((unsigned)f2bf(oy) << 16);
  unsigned q1 = (unsigned)f2bf(oz) | ((unsigned)f2bf(ow) << 16);
  uint2 pk = {q0, q1};
  *(uint2*)&hn[(long)r*1024 + t*4] = pk;
}

// ---------------- patch extraction -> bf16 --------------------------------------------
__global__ void xp_extract(const float* __restrict__ x, unsigned short* __restrict__ xp)
{
  int idx = blockIdx.x * 256 + threadIdx.x;
  int e4 = idx & 63;
  int lt = (idx >> 6) & 511;
  int zz = idx >> 15;
  int e  = e4 << 2;
  int py = e >> 4, px0 = e & 15;
  int hy = lt >> 5, wx = lt & 31;
  float4 v = *(const float4*)&x[((long)zz*256 + hy*16 + py)*512 + wx*16 + px0];
  unsigned q0 = (unsigned)f2bf(v.x) | ((unsigned)f2bf(v.y) << 16);
  unsigned q1 = (unsigned)f2bf(v.z) | ((unsigned)f2bf(v.w) << 16);
  uint2 pk = {q0, q1};
  ((uint2*)xp)[idx] = pk;
}

__global__ void pb2_combine(const float* __restrict__ pb, const float* __restrict__ ve,
                            float* __restrict__ out)
{
  int i = blockIdx.x * 256 + threadIdx.x;
  out[i] = pb[i] + ve[i];
}

__global__ void qproj(const float* __restrict__ vq, const float* __restrict__ wq,
                      float* __restrict__ q)
{
  int n = blockIdx.x * 64 + threadIdx.x;
  float s = 0.f;
  for (int k = 0; k < 1024; ++k) s += vq[k] * wq[(long)k*1024 + n];
  q[n] = s;
}

__global__ void wk_fold(const float* __restrict__ wk, const float* __restrict__ qv,
                        float* __restrict__ wt)
{
  int i = blockIdx.x * 256 + threadIdx.x;
  int h = i & 15, D = i >> 4;
  const float* wr = wk + (long)D*1024 + h*64;
  const float* qr = qv + h*64;
  float s = 0.f;
  #pragma unroll
  for (int d = 0; d < 64; ++d) s += wr[d]*qr[d];
  wt[h*1024 + D] = s;
}

__global__ __launch_bounds__(64)
void agg_attn2(const unsigned short* __restrict__ tok, const unsigned short* __restrict__ vb,
               const float* __restrict__ wt, unsigned short* __restrict__ out)
{
  int l = blockIdx.x, h = blockIdx.y, b = blockIdx.z, t = threadIdx.x;
  const float* wh = wt + h*1024;
  float sc[4];
  #pragma unroll
  for (int v = 0; v < 4; ++v){
    const unsigned short* tr = tok + ((((long)b*4 + v)*512 + l) << 10);
    float s = 0.f;
    #pragma unroll
    for (int j = 0; j < 16; ++j){
      int D = t + j*64;
      s += bf2f(tr[D]) * wh[D];
    }
    #pragma unroll
    for (int o = 32; o; o >>= 1) s += __shfl_xor(s, o);
    sc[v] = s * 0.125f;
  }
  float m = fmaxf(fmaxf(sc[0], sc[1]), fmaxf(sc[2], sc[3]));
  float e0 = __expf(sc[0]-m), e1 = __expf(sc[1]-m), e2 = __expf(sc[2]-m), e3 = __expf(sc[3]-m);
  float inv = 1.0f / (e0 + e1 + e2 + e3);
  long base = (((long)b*4)*512 + l)*1024 + h*64 + t;
  float o = e0*bf2f(vb[base]) + e1*bf2f(vb[base + 512*1024])
          + e2*bf2f(vb[base + 2*512*1024]) + e3*bf2f(vb[base + 3*512*1024]);
  out[(((long)b*512 + l) << 10) + h*64 + t] = f2bf(o * inv);
}

// ---------------- MFMA flash self-attention (bf16 qkv input) --------------------------
// 32 q-rows per block, one (b,h). 4 waves: wave = khalf*2 + mtile.
__global__ __launch_bounds__(256)
void attn_mfma(const unsigned short* __restrict__ qkv, unsigned short* __restrict__ out,
               int N)
{
  int h = blockIdx.y, b = blockIdx.z;
  int row0 = blockIdx.x * 32;
  int t = threadIdx.x;
  int wave = t >> 6, lane = t & 63;
  int ln = lane & 15, kg = lane >> 4;
  int mtile = wave & 1, khalf = wave >> 1;
  const unsigned short* base = qkv + (long)b * N * 3072;

  __shared__ __align__(16) unsigned short Ks[128*72];     // [key][d], bf16, padded
  __shared__ __align__(16) unsigned short Vt[64*136];     // [d][key], bf16, padded
  __shared__ __align__(16) unsigned short Pw[4][16*72];   // per-wave P, [row][key]
  __shared__ float Obuf[4][16][68];
  __shared__ float Mbuf[4][16], Lbuf[4][16];

  // Q fragments (rows row0+mtile*16+ln), scaled by SCALE=0.125 (exact pow2)
  short8 qf[2];
  {
    const unsigned short* qp = base + (long)(row0 + mtile*16 + ln)*3072 + h*64;
    #pragma unroll
    for (int s = 0; s < 2; ++s){
      uint4 qa = *(const uint4*)(qp + s*32 + kg*8);
      unsigned qs[4] = {qa.x, qa.y, qa.z, qa.w};
      short8 q;
      #pragma unroll
      for (int i = 0; i < 4; ++i){
        q[2*i]   = (short)f2bf(bf2f((unsigned short)(qs[i] & 0xffff)) * 0.125f);
        q[2*i+1] = (short)f2bf(bf2f((unsigned short)(qs[i] >> 16)) * 0.125f);
      }
      qf[s] = q;
    }
  }

  f32x4 z = {0.f, 0.f, 0.f, 0.f};
  f32x4 O[4] = {z, z, z, z};
  float mrow[4] = {-1e30f, -1e30f, -1e30f, -1e30f};
  float lrow[4] = {0.f, 0.f, 0.f, 0.f};
  unsigned short* pw = &Pw[wave][0];

  for (int j0 = 0; j0 < N; j0 += 128){
    // ---- stage K [key][72] and V^T [d][136] (straight bf16 copies) ----
    #pragma unroll
    for (int it = 0; it < 2; ++it){
      int key = (t >> 2) + it*64;
      int dg = (t & 3) * 16;
      const unsigned short* kp = base + (long)(j0 + key)*3072 + 1024 + h*64 + dg;
      uint4 ka = *(const uint4*)kp;
      uint4 kb = *(const uint4*)(kp + 8);
      unsigned short* kd = &Ks[key*72 + dg];
      *(uint4*)&kd[0] = ka;
      *(uint4*)&kd[8] = kb;
      const unsigned short* vp = base + (long)(j0 + key)*3072 + 2048 + h*64 + dg;
      uint4 va = *(const uint4*)vp;
      uint4 vb4 = *(const uint4*)(vp + 8);
      unsigned short vv[16];
      vv[0]=(unsigned short)(va.x&0xffff);  vv[1]=(unsigned short)(va.x>>16);
      vv[2]=(unsigned short)(va.y&0xffff);  vv[3]=(unsigned short)(va.y>>16);
      vv[4]=(unsigned short)(va.z&0xffff);  vv[5]=(unsigned short)(va.z>>16);
      vv[6]=(unsigned short)(va.w&0xffff);  vv[7]=(unsigned short)(va.w>>16);
      vv[8]=(unsigned short)(vb4.x&0xffff); vv[9]=(unsigned short)(vb4.x>>16);
      vv[10]=(unsigned short)(vb4.y&0xffff); vv[11]=(unsigned short)(vb4.y>>16);
      vv[12]=(unsigned short)(vb4.z&0xffff); vv[13]=(unsigned short)(vb4.z>>16);
      vv[14]=(unsigned short)(vb4.w&0xffff); vv[15]=(unsigned short)(vb4.w>>16);
      #pragma unroll
      for (int i = 0; i < 16; ++i) Vt[(dg+i)*136 + key] = vv[i];
    }
    __syncthreads();

    // ---- QK^T: S[16 rows][64 keys] for this wave's key sub-tile ----
    f32x4 acc[4] = {z, z, z, z};
    const unsigned short* kbase = &Ks[(khalf*64)*72];
    #pragma unroll
    for (int s = 0; s < 2; ++s){
      #pragma unroll
      for (int nt = 0; nt < 4; ++nt){
        short8 bf = *(const short8*)&kbase[(nt*16 + ln)*72 + s*32 + kg*8];
        acc[nt] = __builtin_amdgcn_mfma_f32_16x16x32_bf16(qf[s], bf, acc[nt], 0, 0, 0);
      }
    }

    // ---- online softmax; lane holds rows kg*4+r, cols nt*16+ln ----
    #pragma unroll
    for (int r = 0; r < 4; ++r){
      float mt = fmaxf(fmaxf(acc[0][r], acc[1][r]), fmaxf(acc[2][r], acc[3][r]));
      #pragma unroll
      for (int o = 1; o < 16; o <<= 1) mt = fmaxf(mt, __shfl_xor(mt, o));
      float m_new = fmaxf(mrow[r], mt);
      float alpha = __expf(mrow[r] - m_new);
      float ps = 0.f;
      #pragma unroll
      for (int nt = 0; nt < 4; ++nt){
        float p = __expf(acc[nt][r] - m_new);
        ps += p;
        pw[(kg*4 + r)*72 + nt*16 + ln] = f2bf(p);
      }
      #pragma unroll
      for (int o = 1; o < 16; o <<= 1) ps += __shfl_xor(ps, o);
      lrow[r] = alpha*lrow[r] + ps;
      mrow[r] = m_new;
      O[0][r] *= alpha; O[1][r] *= alpha; O[2][r] *= alpha; O[3][r] *= alpha;
    }

    // ---- PV: O[16 rows][64 d] += P[16][64] * V[64][64] ----
    #pragma unroll
    for (int s = 0; s < 2; ++s){
      short8 pa = *(const short8*)&pw[ln*72 + s*32 + kg*8];
      #pragma unroll
      for (int dt = 0; dt < 4; ++dt){
        short8 bv = *(const short8*)&Vt[(dt*16 + ln)*136 + khalf*64 + s*32 + kg*8];
        O[dt] = __builtin_amdgcn_mfma_f32_16x16x32_bf16(pa, bv, O[dt], 0, 0, 0);
      }
    }
    __syncthreads();
  }

  // ---- stash per-wave O, m, l; merge key-halves; write bf16 out ----
  #pragma unroll
  for (int dt = 0; dt < 4; ++dt)
    #pragma unroll
    for (int r = 0; r < 4; ++r)
      Obuf[wave][kg*4 + r][dt*16 + ln] = O[dt][r];
  if (ln == 0){
    #pragma unroll
    for (int r = 0; r < 4; ++r){
      Mbuf[wave][kg*4 + r] = mrow[r];
      Lbuf[wave][kg*4 + r] = lrow[r];
    }
  }
  __syncthreads();
  int row = t >> 3, d0 = (t & 7) * 8;
  int wa = row >> 4, lr = row & 15;
  float ma = Mbuf[wa][lr],  mb2 = Mbuf[wa+2][lr];
  float la = Lbuf[wa][lr],  lb  = Lbuf[wa+2][lr];
  float mm = fmaxf(ma, mb2);
  float ea = __expf(ma - mm), eb = __expf(mb2 - mm);
  float linv = 1.0f / (la*ea + lb*eb);
  ea *= linv; eb *= linv;
  float4 a0 = *(const float4*)&Obuf[wa][lr][d0];
  float4 a1 = *(const float4*)&Obuf[wa][lr][d0+4];
  float4 b0 = *(const float4*)&Obuf[wa+2][lr][d0];
  float4 b1 = *(const float4*)&Obuf[wa+2][lr][d0+4];
  float o0 = a0.x*ea + b0.x*eb, o1 = a0.y*ea + b0.y*eb;
  float o2 = a0.z*ea + b0.z*eb, o3 = a0.w*ea + b0.w*eb;
  float o4 = a1.x*ea + b1.x*eb, o5 = a1.y*ea + b1.y*eb;
  float o6 = a1.z*ea + b1.z*eb, o7 = a1.w*ea + b1.w*eb;
  unsigned q0 = (unsigned)f2bf(o0) | ((unsigned)f2bf(o1) << 16);
  unsigned q1 = (unsigned)f2bf(o2) | ((unsigned)f2bf(o3) << 16);
  unsigned q2 = (unsigned)f2bf(o4) | ((unsigned)f2bf(o5) << 16);
  unsigned q3 = (unsigned)f2bf(o6) | ((unsigned)f2bf(o7) << 16);
  uint4 pk = {q0, q1, q2, q3};
  *(uint4*)&out[((long)(b*N + row0 + row))*1024 + h*64 + d0] = pk;
}

// conv1 v4: x (B,4,256,512) -> gelu(conv3x3) -> channels-last bf16 (B,256,512,64)
__global__ __launch_bounds__(256)
void conv1_v4(const float* __restrict__ x, const float* __restrict__ w,
              const float* __restrict__ bi, unsigned short* __restrict__ out)
{
  __shared__ unsigned short obuf[256*68];
  int t = threadIdx.x;
  int id = blockIdx.x*256 + t;   // 262144 pixels
  int px = id & 511, py = (id >> 9) & 255, bb = id >> 17;
  float in[4][9];
  #pragma unroll
  for (int ci = 0; ci < 4; ++ci){
    const float* xc = x + ((long)(bb*4 + ci)*256)*512;
    #pragma unroll
    for (int ky = 0; ky < 3; ++ky){
      int yy = py + ky - 1;
      #pragma unroll
      for (int kx = 0; kx < 3; ++kx){
        int xx = px + kx - 1;
        bool ok = ((unsigned)yy < 256u) && ((unsigned)xx < 512u);
        in[ci][ky*3+kx] = ok ? xc[yy*512 + xx] : 0.f;
      }
    }
  }
  unsigned short* orow = &obuf[t*68];
  #pragma unroll 2
  for (int g = 0; g < 8; ++g){
    unsigned pk[4];
    #pragma unroll
    for (int u = 0; u < 8; ++u){
      int co = g*8 + u;
      float s = bi[co];
      #pragma unroll
      for (int ci = 0; ci < 4; ++ci){
        const float* wc = w + (co*4 + ci)*9;
        #pragma unroll
        for (int k = 0; k < 9; ++k) s += in[ci][k]*wc[k];
      }
      s = gelu_f(s);
      unsigned short h = f2bf(s);
      if (u & 1) pk[u>>1] |= ((unsigned)h << 16);
      else       pk[u>>1]  = (unsigned)h;
    }
    uint2 v0 = {pk[0], pk[1]};
    uint2 v1 = {pk[2], pk[3]};
    *(uint2*)&orow[g*8]     = v0;
    *(uint2*)&orow[g*8 + 4] = v1;
  }
  __syncthreads();
  unsigned short* ob = out + (long)blockIdx.x * (256*64);
  #pragma unroll
  for (int j = 0; j < 8; ++j){
    int u = j*256 + t;
    int p = u >> 3, s4 = u & 7;
    uint2 a  = *(const uint2*)&obuf[p*68 + s4*8];
    uint2 b2 = *(const uint2*)&obuf[p*68 + s4*8 + 4];
    uint4 v = {a.x, a.y, b2.x, b2.y};
    *(uint4*)&ob[(long)u*8] = v;
  }
}

// conv2 v3 (pixel_shuffle fused): r1 bf16 channels-last -> r2 fp32 (B,1024,2048)
__global__ __launch_bounds__(256)
void conv2_v3(const unsigned short* __restrict__ r1, const float* __restrict__ w,
              const float* __restrict__ bi, float* __restrict__ out)
{
  __shared__ float cbuf[108*68];
  int X0 = blockIdx.x*64, Y0 = blockIdx.y*16, bb = blockIdx.z;
  int cx0 = (X0 >> 2) - 1, cy0 = (Y0 >> 2) - 1;
  int t = threadIdx.x;
  const unsigned short* rb = r1 + (long)bb*256*512*64;
  for (int i4 = t; i4 < 1728; i4 += 256){
    int cell = i4 >> 4, ch4 = (i4 & 15) << 2;
    int cy = cy0 + cell/18, cx = cx0 + cell%18;
    float4 v = {0.f, 0.f, 0.f, 0.f};
    if ((unsigned)cy < 256u && (unsigned)cx < 512u){
      uint2 u = *(const uint2*)&rb[(((long)cy*512 + cx) << 6) + ch4];
      v.x = bf2f((unsigned short)(u.x & 0xffff));
      v.y = bf2f((unsigned short)(u.x >> 16));
      v.z = bf2f((unsigned short)(u.y & 0xffff));
      v.w = bf2f((unsigned short)(u.y >> 16));
    }
    *(float4*)&cbuf[cell*68 + ch4] = v;
  }
  float wv[36];
  #pragma unroll
  for (int k = 0; k < 36; ++k) wv[k] = w[k];
  float bias = bi[0];
  __syncthreads();
  int lx = t & 63, tq = t >> 6;
  int X = X0 + lx;
  #pragma unroll
  for (int j = 0; j < 4; ++j){
    int Y = Y0 + tq*4 + j;
    float s = bias;
    #pragma unroll
    for (int ky = 0; ky < 3; ++ky){
      int yy = Y + ky - 1;
      if ((unsigned)yy >= 1024u) continue;
      int ly = (yy >> 2) - cy0, phy = (yy & 3) << 2;
      #pragma unroll
      for (int kx = 0; kx < 3; ++kx){
        int xx = X + kx - 1;
        if ((unsigned)xx >= 2048u) continue;
        int lxc = (xx >> 2) - cx0;
        const float* cp = &cbuf[(ly*18 + lxc)*68 + phy + (xx & 3)];
        s += cp[0]*wv[ky*3+kx] + cp[16]*wv[9+ky*3+kx]
           + cp[32]*wv[18+ky*3+kx] + cp[48]*wv[27+ky*3+kx];
      }
    }
    out[(((long)bb*1024 + Y) << 11) + X] = s;
  }
}

// fused: unpatchify + residual + final 3x3 conv -> d_out
__global__ __launch_bounds__(256)
void cout_fused(const float* __restrict__ pred, const float* __restrict__ r2,
                const float* __restrict__ w, const float* __restrict__ bi,
                float* __restrict__ out)
{
  __shared__ float tb[18*66];
  int X0 = blockIdx.x*64, Y0 = blockIdx.y*16, bb = blockIdx.z;
  int t = threadIdx.x;
  for (int i = t; i < 1188; i += 256){
    int ly = i/66, lx = i%66;
    int Y = Y0 + ly - 1, X = X0 + lx - 1;
    float v = 0.f;
    if ((unsigned)Y < 1024u && (unsigned)X < 2048u){
      int i2 = Y >> 4, p = Y & 15, j2 = X >> 4, q = X & 15;
      int l = i2*8 + (j2 >> 4);
      int e = ((j2 & 15) << 8) + (p << 4) + q;
      v = pred[(((long)bb*512 + l) << 12) + e] + r2[(((long)bb*1024 + Y) << 11) + X];
    }
    tb[i] = v;
  }
  float w0=w[0], w1=w[1], w2=w[2], w3=w[3], w4=w[4], w5=w[5], w6=w[6], w7=w[7], w8=w[8];
  float bias = bi[0];
  __syncthreads();
  int lx = t & 63, tq = t >> 6;
  #pragma unroll
  for (int j = 0; j < 4; ++j){
    int ry = tq*4 + j;
    const float* c = &tb[ry*66 + lx];
    float s = bias + c[0]*w0 + c[1]*w1 + c[2]*w2
            + c[66]*w3 + c[67]*w4 + c[68]*w5
            + c[132]*w6 + c[133]*w7 + c[134]*w8;
    out[(((long)bb*1024 + Y0 + ry) << 11) + X0 + lx] = s;
  }
}

// ---------------------------------------------------------------------------------------
static inline void gemm_go(hipStream_t st, int TM, const unsigned short* A,
                           const unsigned short* Wt,
                           const float* bias, const float* res, float* Cf, unsigned short* Cb,
                           float* Cp, int splits,
                           int M, int N, int K, int batches,
                           long sA, long sW, long sBias, long sRes, long sC,
                           int wmod, int act)
{
  dim3 g(N/128, M/TM, batches*splits);
  long MN = (long)M*N;
  if (TM == 128)
    gemm_bt<128><<<g, 256, 0, st>>>(A, Wt, bias, res, Cf, Cb, Cp, MN, splits,
                                    M, N, K, N, sA, sW, sBias, sRes, sC, wmod, act);
  else
    gemm_bt<64><<<g, 256, 0, st>>>(A, Wt, bias, res, Cf, Cb, Cp, MN, splits,
                                   M, N, K, N, sA, sW, sBias, sRes, sC, wmod, act);
}

static inline void reduce_go(hipStream_t st, const float* Cp, int splits, int nbat,
                             long MN, int N, const float* bias, const float* res, long sRes,
                             float* Cf, unsigned short* Cb, long sC, int act,
                             const int* sidx)
{
  long total4 = (long)nbat*MN/4;
  reduce_ep<<<(int)((total4 + 255)/256), 256, 0, st>>>(Cp, splits, nbat, MN, N,
                                                       bias, res, sRes, Cf, Cb, sC, act,
                                                       sidx);
}

extern "C" void kernel_launch(void* const* d_in, const int* in_sizes, int n_in,
                              void* d_out, int out_size, void* d_ws, size_t ws_size,
                              hipStream_t stream)
{
  const float* x         = (const float*)d_in[0];
  const int*   hard_idx  = (const int*)  d_in[1];
  const float* patch_w   = (const float*)d_in[2];
  const float* patch_b   = (const float*)d_in[3];
  const float* var_embed = (const float*)d_in[4];
  const float* var_query = (const float*)d_in[5];
  const float* agg_wq    = (const float*)d_in[6];
  const float* agg_wk    = (const float*)d_in[7];
  const float* agg_wv    = (const float*)d_in[8];
  const float* agg_wo    = (const float*)d_in[9];
  const float* agg_bo    = (const float*)d_in[10];
  const float* pos_embed = (const float*)d_in[11];
  const float* ln1_w     = (const float*)d_in[12];
  const float* ln1_b     = (const float*)d_in[13];
  const float* qkv_w     = (const float*)d_in[14];
  const float* qkv_b     = (const float*)d_in[15];
  const float* aproj_w   = (const float*)d_in[16];
  const float* aproj_b   = (const float*)d_in[17];
  const float* ln2_w     = (const float*)d_in[18];
  const float* ln2_b     = (const float*)d_in[19];
  const float* fc1_w     = (const float*)d_in[20];
  const float* fc1_b     = (const float*)d_in[21];
  const float* fc2_w     = (const float*)d_in[22];
  const float* fc2_b     = (const float*)d_in[23];
  const float* norm_w    = (const float*)d_in[24];
  const float* norm_b    = (const float*)d_in[25];
  const float* head_w    = (const float*)d_in[26];
  const float* head_b    = (const float*)d_in[27];
  const float* head_out_w= (const float*)d_in[28];
  const float* head_out_b= (const float*)d_in[29];
  const float* p2c1_w    = (const float*)d_in[30];
  const float* p2c1_b    = (const float*)d_in[31];
  const float* p2c2_w    = (const float*)d_in[32];
  const float* p2c2_b    = (const float*)d_in[33];
  const float* cout_w    = (const float*)d_in[34];
  const float* cout_b    = (const float*)d_in[35];

  float* ws = (float*)d_ws;
  float* xt   = ws;                // 1U fp32 stream (B,512,1024)
  float* r2   = ws + 1*UNIT;       // 4U
  float* pred = ws + 8*UNIT;       // 4U (phase3+)
  unsigned short* rbig = (unsigned short*)(ws + 8*UNIT);  // 16.8M bf16 (phase0 only)
  unsigned short* b16 = (unsigned short*)(ws + 16*UNIT);  // 24M ushorts = 12U
  unsigned short* hn_bf    = b16;                // 1M
  unsigned short* ao_bf    = b16 + 1*UNIT;       // 1M
  unsigned short* ff_bf    = b16 + 2*UNIT;       // 4M
  unsigned short* xp_bf    = b16 + 6*UNIT;       // 1M
  unsigned short* tok_bf   = b16 + 7*UNIT;       // 4M
  unsigned short* aggin_bf = b16 + 11*UNIT;      // 1M
  unsigned short* qkvb_bf  = b16 + 12*UNIT;      // 3M (qkv bf16)
  unsigned short* vb_bf    = b16 + 15*UNIT;      // 4M (agg V bf16)
  float* tail = ws + 28*UNIT;
  float* pb2  = tail;              // 4096
  float* qv   = tail + 4096;       // 1024
  float* wtl  = tail + 5120;       // 16384
  float* hbuf = tail + 21504;      // 0.25U
  // mega bf16 weight arena: 81M shorts = 40.5U floats (ws_size = 384MB = 96U)
  unsigned short* wt_all   = (unsigned short*)(ws + 40*UNIT);
  unsigned short* wt_patch = wt_all;              // 1M
  unsigned short* wt_wv    = wt_all + 1*UNIT;     // 1M
  unsigned short* wt_wo    = wt_all + 2*UNIT;     // 1M
  unsigned short* wt_h1    = wt_all + 3*UNIT;     // 1M
  unsigned short* wt_h2    = wt_all + 4*UNIT;     // 1M
  unsigned short* wt_ho    = wt_all + 5*UNIT;     // 4M
  unsigned short* wt_qkv   = wt_all + 9*UNIT;     // 18M (6 x 3M)
  unsigned short* wt_aproj = wt_all + 27*UNIT;    // 6M
  unsigned short* wt_fc1   = wt_all + 33*UNIT;    // 24M
  unsigned short* wt_fc2   = wt_all + 57*UNIT;    // 24M
  float* Cp = ws + 84*UNIT;        // 6U = 24MB split-K partials

  // ---- Phase 0: residual conv path -> r2 ----
  conv1_v4<<<1024, 256, 0, stream>>>(x, p2c1_w, p2c1_b, rbig);
  conv2_v3<<<dim3(32, 64, 2), 256, 0, stream>>>(rbig, p2c2_w, p2c2_b, r2);

  // ---- mega weight transpose (everything, all depths, one launch) ----
  {
    WJobs J;
    const float* Ws[10] = {patch_w, agg_wv, agg_wo, head_w, head_w + 1024L*1024,
                           head_out_w, qkv_w, aproj_w, fc1_w, fc2_w};
    unsigned short* Ts[10] = {wt_patch, wt_wv, wt_wo, wt_h1, wt_h2,
                              wt_ho, wt_qkv, wt_aproj, wt_fc1, wt_fc2};
    int Ks[10]  = {256, 1024, 1024, 1024, 1024, 1024, 1024, 1024, 1024, 4096};
    int Ns[10]  = {1024,1024, 1024, 1024, 1024, 4096, 3072, 1024, 4096, 1024};
    int nbs[10] = {4, 1, 1, 1, 1, 1, 6, 6, 6, 6};
    int acc = 0;
    for (int i = 0; i < 10; ++i){
      J.W[i] = Ws[i]; J.T[i] = Ts[i]; J.K[i] = Ks[i]; J.N[i] = Ns[i];
      J.start[i] = acc;
      acc += nbs[i] * (Ks[i] >> 6) * (Ns[i] >> 5);
    }
    wtrans_multi<<<acc, 256, 0, stream>>>(J);
  }

  // ---- Phase 1: patch embed + aggregate variables -> xt (+ fused ln1 d0) ----
  pb2_combine<<<16, 256, 0, stream>>>(patch_b, var_embed, pb2);
  xp_extract<<<1024, 256, 0, stream>>>(x, xp_bf);
  qproj<<<16, 64, 0, stream>>>(var_query, agg_wq, qv);
  wk_fold<<<64, 256, 0, stream>>>(agg_wk, qv, wtl);
  gemm_go(stream, 128, xp_bf, wt_patch, pb2, nullptr, nullptr, tok_bf, nullptr, 1,
          512, 1024, 256, 8, 512L*256, 256L*1024, 1024, 0, 512L*1024, 4, 0);
  gemm_go(stream, 128, tok_bf, wt_wv, nullptr, nullptr, nullptr, vb_bf, nullptr, 1,
          512, 1024, 1024, 8, 512L*1024, 0, 0, 0, 512L*1024, 1, 0);
  agg_attn2<<<dim3(512, 16, 2), 64, 0, stream>>>(tok_bf, vb_bf, wtl, aggin_bf);
  gemm_go(stream, 64, aggin_bf, wt_wo, nullptr, nullptr, nullptr, nullptr, Cp, 2,
          512, 1024, 1024, 2, 512L*1024, 0, 0, 0, 0, 1, 0);
  reduce_ln<<<1024, 256, 0, stream>>>(Cp, 2, 2, 512L*1024, agg_bo, pos_embed, 0,
                                      xt, ln1_w, ln1_b, hn_bf);

  // ---- Phase 2: transformer blocks (hn_bf = ln1(cur) on entry) ----
  auto run_block = [&](float* cur, int Nt, int d, const float* nw, const float* nbp,
                       int fc2mode){
    int rows = 2 * Nt;
    bool dense = (rows >= 1024);
    int TMbig = dense ? 128 : 64;
    long MNa = (long)rows*1024, MNf = (long)rows*4096;
    int qsk = dense ? 2 : 4;
    gemm_go(stream, TMbig, hn_bf, wt_qkv + (long)d*3*UNIT, nullptr, nullptr, nullptr,
            nullptr, Cp, qsk, rows, 3072, 1024, 1, 0, 0, 0, 0, 0, 1, 0);
    reduce_go(stream, Cp, qsk, 1, (long)rows*3072, 3072, qkv_b + d*3072, nullptr, 0,
              nullptr, qkvb_bf, 0, 0, nullptr);
    attn_mfma<<<dim3(Nt/32, 16, 2), 256, 0, stream>>>(qkvb_bf, ao_bf, Nt);
    int sk = dense ? 4 : 8;
    gemm_go(stream, TMbig, ao_bf, wt_aproj + (long)d*UNIT, nullptr, nullptr, nullptr,
            nullptr, Cp, sk, rows, 1024, 1024, 1, 0, 0, 0, 0, 0, 1, 0);
    reduce_ln<<<rows, 256, 0, stream>>>(Cp, sk, 1, MNa, aproj_b + d*1024, cur, 0,
                                        cur, ln2_w + d*1024, ln2_b + d*1024, hn_bf);
    if (dense){
      gemm_go(stream, 128, hn_bf, wt_fc1 + (long)d*4*UNIT, fc1_b + d*4096, nullptr,
              nullptr, ff_bf, nullptr, 1, rows, 4096, 1024, 1, 0, 0, 0, 0, 0, 1, 1);
    } else {
      gemm_go(stream, 64, hn_bf, wt_fc1 + (long)d*4*UNIT, nullptr, nullptr, nullptr,
              nullptr, Cp, 2, rows, 4096, 1024, 1, 0, 0, 0, 0, 0, 1, 1);
      reduce_go(stream, Cp, 2, 1, MNf, 4096, fc1_b + d*4096, nullptr, 0,
                nullptr, ff_bf, 0, 1, nullptr);
    }
    gemm_go(stream, TMbig, ff_bf, wt_fc2 + (long)d*4*UNIT, nullptr, nullptr, nullptr,
            nullptr, Cp, sk, rows, 1024, 4096, 1, 0, 0, 0, 0, 0, 1, 0);
    if (fc2mode == 0)
      reduce_ln<<<rows, 256, 0, stream>>>(Cp, sk, 1, MNa, fc2_b + d*1024, cur, 0,
                                          cur, nw, nbp, hn_bf);
    else if (fc2mode == 1)
      reduce_go(stream, Cp, sk, 1, MNa, 1024, fc2_b + d*1024, cur, 0,
                cur, nullptr, 0, 0, nullptr);
    else
      reduce_go(stream, Cp, sk, 1, MNa, 1024, fc2_b + d*1024, hbuf, 0,
                xt, nullptr, 0, 0, hard_idx);   // scatter hard rows into xt
  };

  run_block(xt, 512, 0, ln1_w + 1024, ln1_b + 1024, 0);
  run_block(xt, 512, 1, nullptr, nullptr, 1);
  gather_ln<<<256, 256, 0, stream>>>(xt, hard_idx, hbuf,
                                     ln1_w + 2*1024, ln1_b + 2*1024, hn_bf);
  run_block(hbuf, 128, 2, ln1_w + 3*1024, ln1_b + 3*1024, 0);
  run_block(hbuf, 128, 3, ln1_w + 4*1024, ln1_b + 4*1024, 0);
  run_block(hbuf, 128, 4, nullptr, nullptr, 2);
  ln_bf<<<1024, 256, 0, stream>>>(xt, ln1_w + 5*1024, ln1_b + 5*1024, hn_bf);
  run_block(xt, 512, 5, norm_w, norm_b, 0);   // fc2 reduce fused with final norm

  // ---- Phase 3: head (hn_bf = norm(xt) already) ----
  gemm_go(stream, 64, hn_bf, wt_h1, nullptr, nullptr, nullptr, nullptr, Cp, 2,
          1024, 1024, 1024, 1, 0, 0, 0, 0, 0, 1, 1);
  reduce_go(stream, Cp, 2, 1, 1024L*1024, 1024, head_b, nullptr, 0,
            nullptr, ao_bf, 0, 1, nullptr);
  gemm_go(stream, 64, ao_bf, wt_h2, nullptr, nullptr, nullptr, nullptr, Cp, 2,
          1024, 1024, 1024, 1, 0, 0, 0, 0, 0, 1, 1);
  reduce_go(stream, Cp, 2, 1, 1024L*1024, 1024, head_b + 1024, nullptr, 0,
            nullptr, hn_bf, 0, 1, nullptr);
  gemm_go(stream, 128, hn_bf, wt_ho, head_out_b, nullptr, pred, nullptr, nullptr, 1,
          1024, 4096, 1024, 1, 0, 0, 0, 0, 0, 1, 0);

  // ---- Phase 4: fused unpatchify + residual + final conv ----
  cout_fused<<<dim3(32, 64, 2), 256, 0, stream>>>(pred, r2, cout_w, cout_b, (float*)d_out);
}

// Round 5
// 1335.953 us; speedup vs baseline: 1.0124x; 1.0124x over previous
//
#include <hip/hip_runtime.h>
#include <math.h>

// Res_Slim_ViT_Adaptive — r10: wtrans global-vectorization fix.
// ERRATA r9: there was NO write amplification (output is 162MB, WRITE_SIZE matched).
// Real limiter: scalar 4B global loads + small tiles (128B-granular scattered DRAM
// access) -> 2.5 TB/s. r10: 128x128 tiles, float4 reads (512B/row contiguous),
// bf16 LDS [128][130], uint4 writes (256B/row, 16B-aligned). Transpose gather is
// 8 scalar u16 LDS reads per uint4 (~4-way, ~5us aggregate - immaterial).
// Shapes: P=16 D=1024 NH=16 HD=64 MAG=4 B=2 V=4 H=256 W=512 L=512 KEEP=128 DEPTH=6

#define UNIT 1048576L   // 1M elements

typedef __attribute__((ext_vector_type(8))) short short8;
typedef __attribute__((ext_vector_type(4))) float f32x4;

#define GLDS(gp, lp) __builtin_amdgcn_global_load_lds( \
    (const __attribute__((address_space(1))) void*)(gp), \
    (__attribute__((address_space(3))) void*)(lp), 16, 0, 0)

__device__ __forceinline__ float gelu_f(float v){
  return 0.5f*v*(1.0f + erff(v*0.70710678118654752440f));
}

__device__ __forceinline__ unsigned short f2bf(float f){
  union { float f; unsigned u; } a; a.f = f;
  unsigned r = a.u + 0x7fffu + ((a.u >> 16) & 1u);
  return (unsigned short)(r >> 16);
}
__device__ __forceinline__ float bf2f(unsigned short u){
  union { unsigned u; float f; } a; a.u = (unsigned)u << 16;
  return a.f;
}

// =============== mega transpose-convert: W fp32 [K][N] -> Wt bf16 [N][K] ==============
// 128k x 128n tiles. Reads float4 (512B contiguous per k-row), stages bf16 in LDS
// [128][130], writes uint4 (256B contiguous per n-row, 16B aligned).
struct WJobs {
  const float* W[10];
  unsigned short* T[10];
  int K[10], N[10];
  int start[10];
};

__global__ __launch_bounds__(256)
void wtrans_multi(WJobs J)
{
  __shared__ unsigned short T[128*130];   // 33280 B
  int bx = blockIdx.x;
  int j = 0;
  #pragma unroll
  for (int i = 1; i < 10; ++i) if (bx >= J.start[i]) j = i;
  int local = bx - J.start[j];
  int K = J.K[j], N = J.N[j];
  int nx = N >> 7, tpb = (K >> 7) * nx;
  int bz = local / tpb, rem = local % tpb;
  int k0 = (rem / nx) * 128, n0 = (rem % nx) * 128;
  const float* Wp = J.W[j] + (long)bz * K * N;
  unsigned short* Wo = J.T[j] + (long)bz * K * N;
  int t = threadIdx.x;
  int row = t >> 5, c4 = t & 31;          // 8 rows per iter, 32 float4 per row
  #pragma unroll
  for (int i = 0; i < 16; ++i){
    int r = row + i*8;
    float4 v = *(const float4*)&Wp[(long)(k0 + r)*N + n0 + c4*4];
    unsigned lo = (unsigned)f2bf(v.x) | ((unsigned)f2bf(v.y) << 16);
    unsigned hi = (unsigned)f2bf(v.z) | ((unsigned)f2bf(v.w) << 16);
    *(unsigned*)&T[r*130 + c4*4]     = lo;   // byte 260r+8c4: 4B-aligned, 2-way banks
    *(unsigned*)&T[r*130 + c4*4 + 2] = hi;
  }
  __syncthreads();
  int n = t >> 4, c = t & 15;             // 16 n-rows per iter, 16 uint4 per row
  #pragma unroll
  for (int i = 0; i < 8; ++i){
    int nn = n + i*16;
    unsigned pk[4];
    #pragma unroll
    for (int q = 0; q < 4; ++q){
      unsigned lo = T[(c*8 + 2*q)*130 + nn];
      unsigned hi = T[(c*8 + 2*q + 1)*130 + nn];
      pk[q] = lo | (hi << 16);
    }
    uint4 v = {pk[0], pk[1], pk[2], pk[3]};
    *(uint4*)&Wo[(long)(n0 + nn)*K + k0 + c*8] = v;
  }
}

// =============== bf16 MFMA GEMM with optional split-K partial output ==================
// A: bf16 [M][K]; Wt: bf16 [N][K]. Tile TM x 128, BK=32, 256 threads.
template<int TM>
__global__ __launch_bounds__(256)
void gemm_bt(const unsigned short* __restrict__ A, const unsigned short* __restrict__ Wt,
             const float* __restrict__ bias, const float* __restrict__ res,
             float* __restrict__ Cf, unsigned short* __restrict__ Cb,
             float* __restrict__ Cp, long MN, int splits,
             int M, int N, int K, int ldc,
             long sA, long sW, long sBias, long sRes, long sC,
             int wmod, int act)
{
  constexpr int NJ = (TM == 128) ? 4 : 2;
  int bz0 = blockIdx.z;
  int sp = bz0 % splits, bz = bz0 / splits;
  A += (long)bz * sA;
  int wb = bz % wmod;
  Wt += (long)wb * sW;
  const float* bptr = bias ? bias + (long)wb * sBias : nullptr;
  const float* rptr = res  ? res  + (long)bz * sRes : nullptr;
  if (Cf) Cf += (long)bz * sC;
  if (Cb) Cb += (long)bz * sC;

  __shared__ __align__(16) unsigned short As[TM*32];
  __shared__ __align__(16) unsigned short Bs[128*32];

  int t = threadIdx.x;
  int wave = t >> 6, lane = t & 63;
  int ln = lane & 15, kg = lane >> 4;
  int wm, wn;
  if (TM == 128){ wm = (wave & 1) * 64; wn = (wave >> 1) * 64; }
  else          { wm = 0;               wn = wave * 32; }
  int row0 = blockIdx.y * TM, col0 = blockIdx.x * 128;

  f32x4 acc[4][NJ];
  f32x4 z = {0.f, 0.f, 0.f, 0.f};
  #pragma unroll
  for (int i = 0; i < 4; ++i)
    #pragma unroll
    for (int j = 0; j < NJ; ++j) acc[i][j] = z;

  int sm = t >> 2;          // 0..63
  int sk = (t & 3) * 8;     // halfword offset
  unsigned short* AsB = As + wave*512;
  unsigned short* BsB = Bs + wave*512;

  int kpb = K / splits;
  int kbeg = sp * kpb, kend = kbeg + kpb;
  for (int k0 = kbeg; k0 < kend; k0 += 32){
    if (TM == 128){
      GLDS(&A[(long)(row0 + sm)*K + k0 + sk],      AsB);
      GLDS(&A[(long)(row0 + 64 + sm)*K + k0 + sk], AsB + 2048);
    } else {
      GLDS(&A[(long)(row0 + sm)*K + k0 + sk],      AsB);
    }
    GLDS(&Wt[(long)(col0 + sm)*K + k0 + sk],      BsB);
    GLDS(&Wt[(long)(col0 + 64 + sm)*K + k0 + sk], BsB + 2048);
    __syncthreads();
    short8 af[4], bfg[NJ];
    #pragma unroll
    for (int i = 0; i < 4; ++i)  af[i]  = *(const short8*)&As[(wm + i*16 + ln)*32 + kg*8];
    #pragma unroll
    for (int j = 0; j < NJ; ++j) bfg[j] = *(const short8*)&Bs[(wn + j*16 + ln)*32 + kg*8];
    #pragma unroll
    for (int i = 0; i < 4; ++i)
      #pragma unroll
      for (int j = 0; j < NJ; ++j)
        acc[i][j] = __builtin_amdgcn_mfma_f32_16x16x32_bf16(af[i], bfg[j], acc[i][j], 0, 0, 0);
    __syncthreads();
  }

  // C/D layout: col = lane&15, row = (lane>>4)*4 + reg
  if (Cp){
    long nbat = gridDim.z / splits;
    float* P = Cp + ((long)sp*nbat + bz)*MN;
    #pragma unroll
    for (int i = 0; i < 4; ++i){
      int rbase = row0 + wm + i*16 + kg*4;
      #pragma unroll
      for (int j = 0; j < NJ; ++j){
        int c = col0 + wn + j*16 + ln;
        #pragma unroll
        for (int rr2 = 0; rr2 < 4; ++rr2)
          P[(long)(rbase + rr2)*ldc + c] = acc[i][j][rr2];
      }
    }
    return;
  }
  #pragma unroll
  for (int i = 0; i < 4; ++i){
    int rbase = row0 + wm + i*16 + kg*4;
    #pragma unroll
    for (int j = 0; j < NJ; ++j){
      int c = col0 + wn + j*16 + ln;
      float bv = bptr ? bptr[c] : 0.f;
      #pragma unroll
      for (int rr2 = 0; rr2 < 4; ++rr2){
        int rrow = rbase + rr2;
        float v = acc[i][j][rr2] + bv;
        if (rptr) v += rptr[(long)rrow*ldc + c];
        if (act == 1) v = gelu_f(v);
        if (Cf) Cf[(long)rrow*ldc + c] = v;
        if (Cb) Cb[(long)rrow*ldc + c] = f2bf(v);
      }
    }
  }
}

// ---------------- split-K epilogue reduce: sum partials + bias + res + act ------------
// sidx: optional scatter of output rows (N must be 1024): out row = bt*512 + sidx[...]
__global__ __launch_bounds__(256)
void reduce_ep(const float* __restrict__ Cp, int splits, int nbat, long MN, int N,
               const float* __restrict__ bias, const float* __restrict__ res, long sRes,
               float* __restrict__ Cf, unsigned short* __restrict__ Cb, long sC, int act,
               const int* __restrict__ sidx)
{
  long e4 = (long)blockIdx.x*256 + threadIdx.x;
  if (e4 >= (long)nbat*MN/4) return;
  long e = e4 * 4;
  int b = (int)(e / MN); long r = e % MN; int col = (int)(r % N);
  float4 s = *(const float4*)&Cp[(long)b*MN + r];
  for (int sp = 1; sp < splits; ++sp){
    float4 p = *(const float4*)&Cp[((long)sp*nbat + b)*MN + r];
    s.x += p.x; s.y += p.y; s.z += p.z; s.w += p.w;
  }
  if (bias){
    float4 bv = *(const float4*)&bias[col];
    s.x += bv.x; s.y += bv.y; s.z += bv.z; s.w += bv.w;
  }
  if (res){
    float4 rv = *(const float4*)&res[(long)b*sRes + r];
    s.x += rv.x; s.y += rv.y; s.z += rv.z; s.w += rv.w;
  }
  if (act == 1){
    s.x = gelu_f(s.x); s.y = gelu_f(s.y); s.z = gelu_f(s.z); s.w = gelu_f(s.w);
  }
  if (Cf){
    if (sidx){
      int rw = (int)(r >> 10); int bt = rw >> 7, ii = rw & 127;
      long orow = (long)bt*512 + sidx[bt*128 + ii];
      *(float4*)&Cf[orow*1024 + (r & 1023)] = s;
    } else {
      *(float4*)&Cf[(long)b*sC + r] = s;
    }
  }
  if (Cb){
    unsigned q0 = (unsigned)f2bf(s.x) | ((unsigned)f2bf(s.y) << 16);
    unsigned q1 = (unsigned)f2bf(s.z) | ((unsigned)f2bf(s.w) << 16);
    uint2 pk = {q0, q1};
    *(uint2*)&Cb[(long)b*sC + r] = pk;
  }
}

// ---------------- fused split-K reduce + bias + residual + LayerNorm ------------------
// N fixed = 1024. One row per block. Writes fp32 residual stream + bf16 LN output.
__global__ __launch_bounds__(256)
void reduce_ln(const float* __restrict__ Cp, int splits, int nbat, long MN,
               const float* __restrict__ bias,
               const float* __restrict__ res, long sRes,
               float* __restrict__ cur,
               const float* __restrict__ g, const float* __restrict__ b,
               unsigned short* __restrict__ hn)
{
  int row = blockIdx.x;
  int t = threadIdx.x;
  int rpb = (int)(MN >> 10);
  int bb = row / rpb;
  long r = (long)(row - bb*rpb)*1024 + t*4;
  float4 s = *(const float4*)&Cp[(long)bb*MN + r];
  for (int sp = 1; sp < splits; ++sp){
    float4 p = *(const float4*)&Cp[((long)sp*nbat + bb)*MN + r];
    s.x += p.x; s.y += p.y; s.z += p.z; s.w += p.w;
  }
  int col = t*4;
  float4 bv = *(const float4*)&bias[col];
  s.x += bv.x; s.y += bv.y; s.z += bv.z; s.w += bv.w;
  float4 rv = *(const float4*)&res[(long)bb*sRes + r];
  s.x += rv.x; s.y += rv.y; s.z += rv.z; s.w += rv.w;
  *(float4*)&cur[(long)row*1024 + col] = s;
  float sm = s.x + s.y + s.z + s.w;
  float ss = s.x*s.x + s.y*s.y + s.z*s.z + s.w*s.w;
  #pragma unroll
  for (int o = 32; o; o >>= 1){ sm += __shfl_xor(sm, o); ss += __shfl_xor(ss, o); }
  __shared__ float sa[4], sb[4];
  int w = t >> 6, lane = t & 63;
  if (!lane){ sa[w] = sm; sb[w] = ss; }
  __syncthreads();
  sm = sa[0] + sa[1] + sa[2] + sa[3];
  ss = sb[0] + sb[1] + sb[2] + sb[3];
  float mean = sm * (1.0f/1024.0f);
  float var  = ss * (1.0f/1024.0f) - mean*mean;
  float rstd = rsqrtf(var + 1e-5f);
  float4 gv = ((const float4*)g)[t];
  float4 bv2 = ((const float4*)b)[t];
  float ox = (s.x-mean)*rstd*gv.x + bv2.x;
  float oy = (s.y-mean)*rstd*gv.y + bv2.y;
  float oz = (s.z-mean)*rstd*gv.z + bv2.z;
  float ow = (s.w-mean)*rstd*gv.w + bv2.w;
  unsigned q0 = (unsigned)f2bf(ox) | ((unsigned)f2bf(oy) << 16);
  unsigned q1 = (unsigned)f2bf(oz) | ((unsigned)f2bf(ow) << 16);
  uint2 pk = {q0, q1};
  *(uint2*)&hn[(long)row*1024 + col] = pk;
}

// ---------------- LayerNorm over D=1024 -> bf16 out, one row per block ----------------
__global__ __launch_bounds__(256)
void ln_bf(const float* __restrict__ x, const float* __restrict__ g,
           const float* __restrict__ b, unsigned short* __restrict__ y)
{
  long r = blockIdx.x;
  int t = threadIdx.x;
  float4 v = ((const float4*)(x + r*1024))[t];
  float s  = v.x + v.y + v.z + v.w;
  float ss = v.x*v.x + v.y*v.y + v.z*v.z + v.w*v.w;
  #pragma unroll
  for (int o = 32; o; o >>= 1){ s += __shfl_xor(s, o); ss += __shfl_xor(ss, o); }
  __shared__ float sa[4], sb[4];
  int w = t >> 6, lane = t & 63;
  if (!lane){ sa[w] = s; sb[w] = ss; }
  __syncthreads();
  s  = sa[0] + sa[1] + sa[2] + sa[3];
  ss = sb[0] + sb[1] + sb[2] + sb[3];
  float mean = s * (1.0f/1024.0f);
  float var  = ss * (1.0f/1024.0f) - mean*mean;
  float rstd = rsqrtf(var + 1e-5f);
  float4 gv = ((const float4*)g)[t];
  float4 bv = ((const float4*)b)[t];
  float ox = (v.x-mean)*rstd*gv.x + bv.x;
  float oy = (v.y-mean)*rstd*gv.y + bv.y;
  float oz = (v.z-mean)*rstd*gv.z + bv.z;
  float ow = (v.w-mean)*rstd*gv.w + bv.w;
  unsigned q0 = (unsigned)f2bf(ox) | ((unsigned)f2bf(oy) << 16);
  unsigned q1 = (unsigned)f2bf(oz) | ((unsigned)f2bf(ow) << 16);
  uint2 pk = {q0, q1};
  *(uint2*)&y[r*1024 + t*4] = pk;
}

// ---------------- gather hard rows + LayerNorm ----------------------------------------
__global__ __launch_bounds__(256)
void gather_ln(const float* __restrict__ src, const int* __restrict__ idx,
               float* __restrict__ dst, const float* __restrict__ g,
               const float* __restrict__ b, unsigned short* __restrict__ hn)
{
  int r = blockIdx.x, t = threadIdx.x;
  int bb = r >> 7, i = r & 127;
  int s0 = idx[bb*128 + i];
  float4 v = ((const float4*)(src + ((long)bb*512 + s0)*1024))[t];
  ((float4*)(dst + (long)r*1024))[t] = v;
  float s  = v.x + v.y + v.z + v.w;
  float ss = v.x*v.x + v.y*v.y + v.z*v.z + v.w*v.w;
  #pragma unroll
  for (int o = 32; o; o >>= 1){ s += __shfl_xor(s, o); ss += __shfl_xor(ss, o); }
  __shared__ float sa[4], sb[4];
  int w = t >> 6, lane = t & 63;
  if (!lane){ sa[w] = s; sb[w] = ss; }
  __syncthreads();
  s  = sa[0] + sa[1] + sa[2] + sa[3];
  ss = sb[0] + sb[1] + sb[2] + sb[3];
  float mean = s * (1.0f/1024.0f);
  float var  = ss * (1.0f/1024.0f) - mean*mean;
  float rstd = rsqrtf(var + 1e-5f);
  float4 gv = ((const float4*)g)[t];
  float4 bv = ((const float4*)b)[t];
  float ox = (v.x-mean)*rstd*gv.x + bv.x;
  float oy = (v.y-mean)*rstd*gv.y + bv.y;
  float oz = (v.z-mean)*rstd*gv.z + bv.z;
  float ow = (v.w-mean)*rstd*gv.w + bv.w;
  unsigned q0 = (unsigned)f2bf(ox) | ((unsigned)f2bf(oy) << 16);
  unsigned q1 = (unsigned)f2bf(oz) | ((unsigned)f2bf(ow) << 16);
  uint2 pk = {q0, q1};
  *(uint2*)&hn[(long)r*1024 + t*4] = pk;
}

// ---------------- patch extraction -> bf16 --------------------------------------------
__global__ void xp_extract(const float* __restrict__ x, unsigned short* __restrict__ xp)
{
  int idx = blockIdx.x * 256 + threadIdx.x;
  int e4 = idx & 63;
  int lt = (idx >> 6) & 511;
  int zz = idx >> 15;
  int e  = e4 << 2;
  int py = e >> 4, px0 = e & 15;
  int hy = lt >> 5, wx = lt & 31;
  float4 v = *(const float4*)&x[((long)zz*256 + hy*16 + py)*512 + wx*16 + px0];
  unsigned q0 = (unsigned)f2bf(v.x) | ((unsigned)f2bf(v.y) << 16);
  unsigned q1 = (unsigned)f2bf(v.z) | ((unsigned)f2bf(v.w) << 16);
  uint2 pk = {q0, q1};
  ((uint2*)xp)[idx] = pk;
}

__global__ void pb2_combine(const float* __restrict__ pb, const float* __restrict__ ve,
                            float* __restrict__ out)
{
  int i = blockIdx.x * 256 + threadIdx.x;
  out[i] = pb[i] + ve[i];
}

__global__ void qproj(const float* __restrict__ vq, const float* __restrict__ wq,
                      float* __restrict__ q)
{
  int n = blockIdx.x * 64 + threadIdx.x;
  float s = 0.f;
  for (int k = 0; k < 1024; ++k) s += vq[k] * wq[(long)k*1024 + n];
  q[n] = s;
}

__global__ void wk_fold(const float* __restrict__ wk, const float* __restrict__ qv,
                        float* __restrict__ wt)
{
  int i = blockIdx.x * 256 + threadIdx.x;
  int h = i & 15, D = i >> 4;
  const float* wr = wk + (long)D*1024 + h*64;
  const float* qr = qv + h*64;
  float s = 0.f;
  #pragma unroll
  for (int d = 0; d < 64; ++d) s += wr[d]*qr[d];
  wt[h*1024 + D] = s;
}

__global__ __launch_bounds__(64)
void agg_attn2(const unsigned short* __restrict__ tok, const unsigned short* __restrict__ vb,
               const float* __restrict__ wt, unsigned short* __restrict__ out)
{
  int l = blockIdx.x, h = blockIdx.y, b = blockIdx.z, t = threadIdx.x;
  const float* wh = wt + h*1024;
  float sc[4];
  #pragma unroll
  for (int v = 0; v < 4; ++v){
    const unsigned short* tr = tok + ((((long)b*4 + v)*512 + l) << 10);
    float s = 0.f;
    #pragma unroll
    for (int j = 0; j < 16; ++j){
      int D = t + j*64;
      s += bf2f(tr[D]) * wh[D];
    }
    #pragma unroll
    for (int o = 32; o; o >>= 1) s += __shfl_xor(s, o);
    sc[v] = s * 0.125f;
  }
  float m = fmaxf(fmaxf(sc[0], sc[1]), fmaxf(sc[2], sc[3]));
  float e0 = __expf(sc[0]-m), e1 = __expf(sc[1]-m), e2 = __expf(sc[2]-m), e3 = __expf(sc[3]-m);
  float inv = 1.0f / (e0 + e1 + e2 + e3);
  long base = (((long)b*4)*512 + l)*1024 + h*64 + t;
  float o = e0*bf2f(vb[base]) + e1*bf2f(vb[base + 512*1024])
          + e2*bf2f(vb[base + 2*512*1024]) + e3*bf2f(vb[base + 3*512*1024]);
  out[(((long)b*512 + l) << 10) + h*64 + t] = f2bf(o * inv);
}

// ---------------- MFMA flash self-attention (bf16 qkv input) --------------------------
// 32 q-rows per block, one (b,h). 4 waves: wave = khalf*2 + mtile.
__global__ __launch_bounds__(256)
void attn_mfma(const unsigned short* __restrict__ qkv, unsigned short* __restrict__ out,
               int N)
{
  int h = blockIdx.y, b = blockIdx.z;
  int row0 = blockIdx.x * 32;
  int t = threadIdx.x;
  int wave = t >> 6, lane = t & 63;
  int ln = lane & 15, kg = lane >> 4;
  int mtile = wave & 1, khalf = wave >> 1;
  const unsigned short* base = qkv + (long)b * N * 3072;

  __shared__ __align__(16) unsigned short Ks[128*72];     // [key][d], bf16, padded
  __shared__ __align__(16) unsigned short Vt[64*136];     // [d][key], bf16, padded
  __shared__ __align__(16) unsigned short Pw[4][16*72];   // per-wave P, [row][key]
  __shared__ float Obuf[4][16][68];
  __shared__ float Mbuf[4][16], Lbuf[4][16];

  // Q fragments (rows row0+mtile*16+ln), scaled by SCALE=0.125 (exact pow2)
  short8 qf[2];
  {
    const unsigned short* qp = base + (long)(row0 + mtile*16 + ln)*3072 + h*64;
    #pragma unroll
    for (int s = 0; s < 2; ++s){
      uint4 qa = *(const uint4*)(qp + s*32 + kg*8);
      unsigned qs[4] = {qa.x, qa.y, qa.z, qa.w};
      short8 q;
      #pragma unroll
      for (int i = 0; i < 4; ++i){
        q[2*i]   = (short)f2bf(bf2f((unsigned short)(qs[i] & 0xffff)) * 0.125f);
        q[2*i+1] = (short)f2bf(bf2f((unsigned short)(qs[i] >> 16)) * 0.125f);
      }
      qf[s] = q;
    }
  }

  f32x4 z = {0.f, 0.f, 0.f, 0.f};
  f32x4 O[4] = {z, z, z, z};
  float mrow[4] = {-1e30f, -1e30f, -1e30f, -1e30f};
  float lrow[4] = {0.f, 0.f, 0.f, 0.f};
  unsigned short* pw = &Pw[wave][0];

  for (int j0 = 0; j0 < N; j0 += 128){
    // ---- stage K [key][72] and V^T [d][136] (straight bf16 copies) ----
    #pragma unroll
    for (int it = 0; it < 2; ++it){
      int key = (t >> 2) + it*64;
      int dg = (t & 3) * 16;
      const unsigned short* kp = base + (long)(j0 + key)*3072 + 1024 + h*64 + dg;
      uint4 ka = *(const uint4*)kp;
      uint4 kb = *(const uint4*)(kp + 8);
      unsigned short* kd = &Ks[key*72 + dg];
      *(uint4*)&kd[0] = ka;
      *(uint4*)&kd[8] = kb;
      const unsigned short* vp = base + (long)(j0 + key)*3072 + 2048 + h*64 + dg;
      uint4 va = *(const uint4*)vp;
      uint4 vb4 = *(const uint4*)(vp + 8);
      unsigned short vv[16];
      vv[0]=(unsigned short)(va.x&0xffff);  vv[1]=(unsigned short)(va.x>>16);
      vv[2]=(unsigned short)(va.y&0xffff);  vv[3]=(unsigned short)(va.y>>16);
      vv[4]=(unsigned short)(va.z&0xffff);  vv[5]=(unsigned short)(va.z>>16);
      vv[6]=(unsigned short)(va.w&0xffff);  vv[7]=(unsigned short)(va.w>>16);
      vv[8]=(unsigned short)(vb4.x&0xffff); vv[9]=(unsigned short)(vb4.x>>16);
      vv[10]=(unsigned short)(vb4.y&0xffff); vv[11]=(unsigned short)(vb4.y>>16);
      vv[12]=(unsigned short)(vb4.z&0xffff); vv[13]=(unsigned short)(vb4.z>>16);
      vv[14]=(unsigned short)(vb4.w&0xffff); vv[15]=(unsigned short)(vb4.w>>16);
      #pragma unroll
      for (int i = 0; i < 16; ++i) Vt[(dg+i)*136 + key] = vv[i];
    }
    __syncthreads();

    // ---- QK^T: S[16 rows][64 keys] for this wave's key sub-tile ----
    f32x4 acc[4] = {z, z, z, z};
    const unsigned short* kbase = &Ks[(khalf*64)*72];
    #pragma unroll
    for (int s = 0; s < 2; ++s){
      #pragma unroll
      for (int nt = 0; nt < 4; ++nt){
        short8 bf = *(const short8*)&kbase[(nt*16 + ln)*72 + s*32 + kg*8];
        acc[nt] = __builtin_amdgcn_mfma_f32_16x16x32_bf16(qf[s], bf, acc[nt], 0, 0, 0);
      }
    }

    // ---- online softmax; lane holds rows kg*4+r, cols nt*16+ln ----
    #pragma unroll
    for (int r = 0; r < 4; ++r){
      float mt = fmaxf(fmaxf(acc[0][r], acc[1][r]), fmaxf(acc[2][r], acc[3][r]));
      #pragma unroll
      for (int o = 1; o < 16; o <<= 1) mt = fmaxf(mt, __shfl_xor(mt, o));
      float m_new = fmaxf(mrow[r], mt);
      float alpha = __expf(mrow[r] - m_new);
      float ps = 0.f;
      #pragma unroll
      for (int nt = 0; nt < 4; ++nt){
        float p = __expf(acc[nt][r] - m_new);
        ps += p;
        pw[(kg*4 + r)*72 + nt*16 + ln] = f2bf(p);
      }
      #pragma unroll
      for (int o = 1; o < 16; o <<= 1) ps += __shfl_xor(ps, o);
      lrow[r] = alpha*lrow[r] + ps;
      mrow[r] = m_new;
      O[0][r] *= alpha; O[1][r] *= alpha; O[2][r] *= alpha; O[3][r] *= alpha;
    }

    // ---- PV: O[16 rows][64 d] += P[16][64] * V[64][64] ----
    #pragma unroll
    for (int s = 0; s < 2; ++s){
      short8 pa = *(const short8*)&pw[ln*72 + s*32 + kg*8];
      #pragma unroll
      for (int dt = 0; dt < 4; ++dt){
        short8 bv = *(const short8*)&Vt[(dt*16 + ln)*136 + khalf*64 + s*32 + kg*8];
        O[dt] = __builtin_amdgcn_mfma_f32_16x16x32_bf16(pa, bv, O[dt], 0, 0, 0);
      }
    }
    __syncthreads();
  }

  // ---- stash per-wave O, m, l; merge key-halves; write bf16 out ----
  #pragma unroll
  for (int dt = 0; dt < 4; ++dt)
    #pragma unroll
    for (int r = 0; r < 4; ++r)
      Obuf[wave][kg*4 + r][dt*16 + ln] = O[dt][r];
  if (ln == 0){
    #pragma unroll
    for (int r = 0; r < 4; ++r){
      Mbuf[wave][kg*4 + r] = mrow[r];
      Lbuf[wave][kg*4 + r] = lrow[r];
    }
  }
  __syncthreads();
  int row = t >> 3, d0 = (t & 7) * 8;
  int wa = row >> 4, lr = row & 15;
  float ma = Mbuf[wa][lr],  mb2 = Mbuf[wa+2][lr];
  float la = Lbuf[wa][lr],  lb  = Lbuf[wa+2][lr];
  float mm = fmaxf(ma, mb2);
  float ea = __expf(ma - mm), eb = __expf(mb2 - mm);
  float linv = 1.0f / (la*ea + lb*eb);
  ea *= linv; eb *= linv;
  float4 a0 = *(const float4*)&Obuf[wa][lr][d0];
  float4 a1 = *(const float4*)&Obuf[wa][lr][d0+4];
  float4 b0 = *(const float4*)&Obuf[wa+2][lr][d0];
  float4 b1 = *(const float4*)&Obuf[wa+2][lr][d0+4];
  float o0 = a0.x*ea + b0.x*eb, o1 = a0.y*ea + b0.y*eb;
  float o2 = a0.z*ea + b0.z*eb, o3 = a0.w*ea + b0.w*eb;
  float o4 = a1.x*ea + b1.x*eb, o5 = a1.y*ea + b1.y*eb;
  float o6 = a1.z*ea + b1.z*eb, o7 = a1.w*ea + b1.w*eb;
  unsigned q0 = (unsigned)f2bf(o0) | ((unsigned)f2bf(o1) << 16);
  unsigned q1 = (unsigned)f2bf(o2) | ((unsigned)f2bf(o3) << 16);
  unsigned q2 = (unsigned)f2bf(o4) | ((unsigned)f2bf(o5) << 16);
  unsigned q3 = (unsigned)f2bf(o6) | ((unsigned)f2bf(o7) << 16);
  uint4 pk = {q0, q1, q2, q3};
  *(uint4*)&out[((long)(b*N + row0 + row))*1024 + h*64 + d0] = pk;
}

// conv1 v4: x (B,4,256,512) -> gelu(conv3x3) -> channels-last bf16 (B,256,512,64)
__global__ __launch_bounds__(256)
void conv1_v4(const float* __restrict__ x, const float* __restrict__ w,
              const float* __restrict__ bi, unsigned short* __restrict__ out)
{
  __shared__ unsigned short obuf[256*68];
  int t = threadIdx.x;
  int id = blockIdx.x*256 + t;   // 262144 pixels
  int px = id & 511, py = (id >> 9) & 255, bb = id >> 17;
  float in[4][9];
  #pragma unroll
  for (int ci = 0; ci < 4; ++ci){
    const float* xc = x + ((long)(bb*4 + ci)*256)*512;
    #pragma unroll
    for (int ky = 0; ky < 3; ++ky){
      int yy = py + ky - 1;
      #pragma unroll
      for (int kx = 0; kx < 3; ++kx){
        int xx = px + kx - 1;
        bool ok = ((unsigned)yy < 256u) && ((unsigned)xx < 512u);
        in[ci][ky*3+kx] = ok ? xc[yy*512 + xx] : 0.f;
      }
    }
  }
  unsigned short* orow = &obuf[t*68];
  #pragma unroll 2
  for (int g = 0; g < 8; ++g){
    unsigned pk[4];
    #pragma unroll
    for (int u = 0; u < 8; ++u){
      int co = g*8 + u;
      float s = bi[co];
      #pragma unroll
      for (int ci = 0; ci < 4; ++ci){
        const float* wc = w + (co*4 + ci)*9;
        #pragma unroll
        for (int k = 0; k < 9; ++k) s += in[ci][k]*wc[k];
      }
      s = gelu_f(s);
      unsigned short h = f2bf(s);
      if (u & 1) pk[u>>1] |= ((unsigned)h << 16);
      else       pk[u>>1]  = (unsigned)h;
    }
    uint2 v0 = {pk[0], pk[1]};
    uint2 v1 = {pk[2], pk[3]};
    *(uint2*)&orow[g*8]     = v0;
    *(uint2*)&orow[g*8 + 4] = v1;
  }
  __syncthreads();
  unsigned short* ob = out + (long)blockIdx.x * (256*64);
  #pragma unroll
  for (int j = 0; j < 8; ++j){
    int u = j*256 + t;
    int p = u >> 3, s4 = u & 7;
    uint2 a  = *(const uint2*)&obuf[p*68 + s4*8];
    uint2 b2 = *(const uint2*)&obuf[p*68 + s4*8 + 4];
    uint4 v = {a.x, a.y, b2.x, b2.y};
    *(uint4*)&ob[(long)u*8] = v;
  }
}

// conv2 v3 (pixel_shuffle fused): r1 bf16 channels-last -> r2 fp32 (B,1024,2048)
__global__ __launch_bounds__(256)
void conv2_v3(const unsigned short* __restrict__ r1, const float* __restrict__ w,
              const float* __restrict__ bi, float* __restrict__ out)
{
  __shared__ float cbuf[108*68];
  int X0 = blockIdx.x*64, Y0 = blockIdx.y*16, bb = blockIdx.z;
  int cx0 = (X0 >> 2) - 1, cy0 = (Y0 >> 2) - 1;
  int t = threadIdx.x;
  const unsigned short* rb = r1 + (long)bb*256*512*64;
  for (int i4 = t; i4 < 1728; i4 += 256){
    int cell = i4 >> 4, ch4 = (i4 & 15) << 2;
    int cy = cy0 + cell/18, cx = cx0 + cell%18;
    float4 v = {0.f, 0.f, 0.f, 0.f};
    if ((unsigned)cy < 256u && (unsigned)cx < 512u){
      uint2 u = *(const uint2*)&rb[(((long)cy*512 + cx) << 6) + ch4];
      v.x = bf2f((unsigned short)(u.x & 0xffff));
      v.y = bf2f((unsigned short)(u.x >> 16));
      v.z = bf2f((unsigned short)(u.y & 0xffff));
      v.w = bf2f((unsigned short)(u.y >> 16));
    }
    *(float4*)&cbuf[cell*68 + ch4] = v;
  }
  float wv[36];
  #pragma unroll
  for (int k = 0; k < 36; ++k) wv[k] = w[k];
  float bias = bi[0];
  __syncthreads();
  int lx = t & 63, tq = t >> 6;
  int X = X0 + lx;
  #pragma unroll
  for (int j = 0; j < 4; ++j){
    int Y = Y0 + tq*4 + j;
    float s = bias;
    #pragma unroll
    for (int ky = 0; ky < 3; ++ky){
      int yy = Y + ky - 1;
      if ((unsigned)yy >= 1024u) continue;
      int ly = (yy >> 2) - cy0, phy = (yy & 3) << 2;
      #pragma unroll
      for (int kx = 0; kx < 3; ++kx){
        int xx = X + kx - 1;
        if ((unsigned)xx >= 2048u) continue;
        int lxc = (xx >> 2) - cx0;
        const float* cp = &cbuf[(ly*18 + lxc)*68 + phy + (xx & 3)];
        s += cp[0]*wv[ky*3+kx] + cp[16]*wv[9+ky*3+kx]
           + cp[32]*wv[18+ky*3+kx] + cp[48]*wv[27+ky*3+kx];
      }
    }
    out[(((long)bb*1024 + Y) << 11) + X] = s;
  }
}

// fused: unpatchify + residual + final 3x3 conv -> d_out
__global__ __launch_bounds__(256)
void cout_fused(const float* __restrict__ pred, const float* __restrict__ r2,
                const float* __restrict__ w, const float* __restrict__ bi,
                float* __restrict__ out)
{
  __shared__ float tb[18*66];
  int X0 = blockIdx.x*64, Y0 = blockIdx.y*16, bb = blockIdx.z;
  int t = threadIdx.x;
  for (int i = t; i < 1188; i += 256){
    int ly = i/66, lx = i%66;
    int Y = Y0 + ly - 1, X = X0 + lx - 1;
    float v = 0.f;
    if ((unsigned)Y < 1024u && (unsigned)X < 2048u){
      int i2 = Y >> 4, p = Y & 15, j2 = X >> 4, q = X & 15;
      int l = i2*8 + (j2 >> 4);
      int e = ((j2 & 15) << 8) + (p << 4) + q;
      v = pred[(((long)bb*512 + l) << 12) + e] + r2[(((long)bb*1024 + Y) << 11) + X];
    }
    tb[i] = v;
  }
  float w0=w[0], w1=w[1], w2=w[2], w3=w[3], w4=w[4], w5=w[5], w6=w[6], w7=w[7], w8=w[8];
  float bias = bi[0];
  __syncthreads();
  int lx = t & 63, tq = t >> 6;
  #pragma unroll
  for (int j = 0; j < 4; ++j){
    int ry = tq*4 + j;
    const float* c = &tb[ry*66 + lx];
    float s = bias + c[0]*w0 + c[1]*w1 + c[2]*w2
            + c[66]*w3 + c[67]*w4 + c[68]*w5
            + c[132]*w6 + c[133]*w7 + c[134]*w8;
    out[(((long)bb*1024 + Y0 + ry) << 11) + X0 + lx] = s;
  }
}

// ---------------------------------------------------------------------------------------
static inline void gemm_go(hipStream_t st, int TM, const unsigned short* A,
                           const unsigned short* Wt,
                           const float* bias, const float* res, float* Cf, unsigned short* Cb,
                           float* Cp, int splits,
                           int M, int N, int K, int batches,
                           long sA, long sW, long sBias, long sRes, long sC,
                           int wmod, int act)
{
  dim3 g(N/128, M/TM, batches*splits);
  long MN = (long)M*N;
  if (TM == 128)
    gemm_bt<128><<<g, 256, 0, st>>>(A, Wt, bias, res, Cf, Cb, Cp, MN, splits,
                                    M, N, K, N, sA, sW, sBias, sRes, sC, wmod, act);
  else
    gemm_bt<64><<<g, 256, 0, st>>>(A, Wt, bias, res, Cf, Cb, Cp, MN, splits,
                                   M, N, K, N, sA, sW, sBias, sRes, sC, wmod, act);
}

static inline void reduce_go(hipStream_t st, const float* Cp, int splits, int nbat,
                             long MN, int N, const float* bias, const float* res, long sRes,
                             float* Cf, unsigned short* Cb, long sC, int act,
                             const int* sidx)
{
  long total4 = (long)nbat*MN/4;
  reduce_ep<<<(int)((total4 + 255)/256), 256, 0, st>>>(Cp, splits, nbat, MN, N,
                                                       bias, res, sRes, Cf, Cb, sC, act,
                                                       sidx);
}

extern "C" void kernel_launch(void* const* d_in, const int* in_sizes, int n_in,
                              void* d_out, int out_size, void* d_ws, size_t ws_size,
                              hipStream_t stream)
{
  const float* x         = (const float*)d_in[0];
  const int*   hard_idx  = (const int*)  d_in[1];
  const float* patch_w   = (const float*)d_in[2];
  const float* patch_b   = (const float*)d_in[3];
  const float* var_embed = (const float*)d_in[4];
  const float* var_query = (const float*)d_in[5];
  const float* agg_wq    = (const float*)d_in[6];
  const float* agg_wk    = (const float*)d_in[7];
  const float* agg_wv    = (const float*)d_in[8];
  const float* agg_wo    = (const float*)d_in[9];
  const float* agg_bo    = (const float*)d_in[10];
  const float* pos_embed = (const float*)d_in[11];
  const float* ln1_w     = (const float*)d_in[12];
  const float* ln1_b     = (const float*)d_in[13];
  const float* qkv_w     = (const float*)d_in[14];
  const float* qkv_b     = (const float*)d_in[15];
  const float* aproj_w   = (const float*)d_in[16];
  const float* aproj_b   = (const float*)d_in[17];
  const float* ln2_w     = (const float*)d_in[18];
  const float* ln2_b     = (const float*)d_in[19];
  const float* fc1_w     = (const float*)d_in[20];
  const float* fc1_b     = (const float*)d_in[21];
  const float* fc2_w     = (const float*)d_in[22];
  const float* fc2_b     = (const float*)d_in[23];
  const float* norm_w    = (const float*)d_in[24];
  const float* norm_b    = (const float*)d_in[25];
  const float* head_w    = (const float*)d_in[26];
  const float* head_b    = (const float*)d_in[27];
  const float* head_out_w= (const float*)d_in[28];
  const float* head_out_b= (const float*)d_in[29];
  const float* p2c1_w    = (const float*)d_in[30];
  const float* p2c1_b    = (const float*)d_in[31];
  const float* p2c2_w    = (const float*)d_in[32];
  const float* p2c2_b    = (const float*)d_in[33];
  const float* cout_w    = (const float*)d_in[34];
  const float* cout_b    = (const float*)d_in[35];

  float* ws = (float*)d_ws;
  float* xt   = ws;                // 1U fp32 stream (B,512,1024)
  float* r2   = ws + 1*UNIT;       // 4U
  float* pred = ws + 8*UNIT;       // 4U (phase3+)
  unsigned short* rbig = (unsigned short*)(ws + 8*UNIT);  // 16.8M bf16 (phase0 only)
  unsigned short* b16 = (unsigned short*)(ws + 16*UNIT);  // 24M ushorts = 12U
  unsigned short* hn_bf    = b16;                // 1M
  unsigned short* ao_bf    = b16 + 1*UNIT;       // 1M
  unsigned short* ff_bf    = b16 + 2*UNIT;       // 4M
  unsigned short* xp_bf    = b16 + 6*UNIT;       // 1M
  unsigned short* tok_bf   = b16 + 7*UNIT;       // 4M
  unsigned short* aggin_bf = b16 + 11*UNIT;      // 1M
  unsigned short* qkvb_bf  = b16 + 12*UNIT;      // 3M (qkv bf16)
  unsigned short* vb_bf    = b16 + 15*UNIT;      // 4M (agg V bf16)
  float* tail = ws + 28*UNIT;
  float* pb2  = tail;              // 4096
  float* qv   = tail + 4096;       // 1024
  float* wtl  = tail + 5120;       // 16384
  float* hbuf = tail + 21504;      // 0.25U
  // mega bf16 weight arena: 81M shorts = 40.5U floats (ws_size = 384MB = 96U)
  unsigned short* wt_all   = (unsigned short*)(ws + 40*UNIT);
  unsigned short* wt_patch = wt_all;              // 1M
  unsigned short* wt_wv    = wt_all + 1*UNIT;     // 1M
  unsigned short* wt_wo    = wt_all + 2*UNIT;     // 1M
  unsigned short* wt_h1    = wt_all + 3*UNIT;     // 1M
  unsigned short* wt_h2    = wt_all + 4*UNIT;     // 1M
  unsigned short* wt_ho    = wt_all + 5*UNIT;     // 4M
  unsigned short* wt_qkv   = wt_all + 9*UNIT;     // 18M (6 x 3M)
  unsigned short* wt_aproj = wt_all + 27*UNIT;    // 6M
  unsigned short* wt_fc1   = wt_all + 33*UNIT;    // 24M
  unsigned short* wt_fc2   = wt_all + 57*UNIT;    // 24M
  float* Cp = ws + 84*UNIT;        // 6U = 24MB split-K partials

  // ---- Phase 0: residual conv path -> r2 ----
  conv1_v4<<<1024, 256, 0, stream>>>(x, p2c1_w, p2c1_b, rbig);
  conv2_v3<<<dim3(32, 64, 2), 256, 0, stream>>>(rbig, p2c2_w, p2c2_b, r2);

  // ---- mega weight transpose (everything, all depths, one launch) ----
  {
    WJobs J;
    const float* Ws[10] = {patch_w, agg_wv, agg_wo, head_w, head_w + 1024L*1024,
                           head_out_w, qkv_w, aproj_w, fc1_w, fc2_w};
    unsigned short* Ts[10] = {wt_patch, wt_wv, wt_wo, wt_h1, wt_h2,
                              wt_ho, wt_qkv, wt_aproj, wt_fc1, wt_fc2};
    int Ks[10]  = {256, 1024, 1024, 1024, 1024, 1024, 1024, 1024, 1024, 4096};
    int Ns[10]  = {1024,1024, 1024, 1024, 1024, 4096, 3072, 1024, 4096, 1024};
    int nbs[10] = {4, 1, 1, 1, 1, 1, 6, 6, 6, 6};
    int acc = 0;
    for (int i = 0; i < 10; ++i){
      J.W[i] = Ws[i]; J.T[i] = Ts[i]; J.K[i] = Ks[i]; J.N[i] = Ns[i];
      J.start[i] = acc;
      acc += nbs[i] * (Ks[i] >> 7) * (Ns[i] >> 7);
    }
    wtrans_multi<<<acc, 256, 0, stream>>>(J);
  }

  // ---- Phase 1: patch embed + aggregate variables -> xt (+ fused ln1 d0) ----
  pb2_combine<<<16, 256, 0, stream>>>(patch_b, var_embed, pb2);
  xp_extract<<<1024, 256, 0, stream>>>(x, xp_bf);
  qproj<<<16, 64, 0, stream>>>(var_query, agg_wq, qv);
  wk_fold<<<64, 256, 0, stream>>>(agg_wk, qv, wtl);
  gemm_go(stream, 128, xp_bf, wt_patch, pb2, nullptr, nullptr, tok_bf, nullptr, 1,
          512, 1024, 256, 8, 512L*256, 256L*1024, 1024, 0, 512L*1024, 4, 0);
  gemm_go(stream, 128, tok_bf, wt_wv, nullptr, nullptr, nullptr, vb_bf, nullptr, 1,
          512, 1024, 1024, 8, 512L*1024, 0, 0, 0, 512L*1024, 1, 0);
  agg_attn2<<<dim3(512, 16, 2), 64, 0, stream>>>(tok_bf, vb_bf, wtl, aggin_bf);
  gemm_go(stream, 64, aggin_bf, wt_wo, nullptr, nullptr, nullptr, nullptr, Cp, 2,
          512, 1024, 1024, 2, 512L*1024, 0, 0, 0, 0, 1, 0);
  reduce_ln<<<1024, 256, 0, stream>>>(Cp, 2, 2, 512L*1024, agg_bo, pos_embed, 0,
                                      xt, ln1_w, ln1_b, hn_bf);

  // ---- Phase 2: transformer blocks (hn_bf = ln1(cur) on entry) ----
  auto run_block = [&](float* cur, int Nt, int d, const float* nw, const float* nbp,
                       int fc2mode){
    int rows = 2 * Nt;
    bool dense = (rows >= 1024);
    int TMbig = dense ? 128 : 64;
    long MNa = (long)rows*1024, MNf = (long)rows*4096;
    int qsk = dense ? 2 : 4;
    gemm_go(stream, TMbig, hn_bf, wt_qkv + (long)d*3*UNIT, nullptr, nullptr, nullptr,
            nullptr, Cp, qsk, rows, 3072, 1024, 1, 0, 0, 0, 0, 0, 1, 0);
    reduce_go(stream, Cp, qsk, 1, (long)rows*3072, 3072, qkv_b + d*3072, nullptr, 0,
              nullptr, qkvb_bf, 0, 0, nullptr);
    attn_mfma<<<dim3(Nt/32, 16, 2), 256, 0, stream>>>(qkvb_bf, ao_bf, Nt);
    int sk = dense ? 4 : 8;
    gemm_go(stream, TMbig, ao_bf, wt_aproj + (long)d*UNIT, nullptr, nullptr, nullptr,
            nullptr, Cp, sk, rows, 1024, 1024, 1, 0, 0, 0, 0, 0, 1, 0);
    reduce_ln<<<rows, 256, 0, stream>>>(Cp, sk, 1, MNa, aproj_b + d*1024, cur, 0,
                                        cur, ln2_w + d*1024, ln2_b + d*1024, hn_bf);
    if (dense){
      gemm_go(stream, 128, hn_bf, wt_fc1 + (long)d*4*UNIT, fc1_b + d*4096, nullptr,
              nullptr, ff_bf, nullptr, 1, rows, 4096, 1024, 1, 0, 0, 0, 0, 0, 1, 1);
    } else {
      gemm_go(stream, 64, hn_bf, wt_fc1 + (long)d*4*UNIT, nullptr, nullptr, nullptr,
              nullptr, Cp, 2, rows, 4096, 1024, 1, 0, 0, 0, 0, 0, 1, 1);
      reduce_go(stream, Cp, 2, 1, MNf, 4096, fc1_b + d*4096, nullptr, 0,
                nullptr, ff_bf, 0, 1, nullptr);
    }
    gemm_go(stream, TMbig, ff_bf, wt_fc2 + (long)d*4*UNIT, nullptr, nullptr, nullptr,
            nullptr, Cp, sk, rows, 1024, 4096, 1, 0, 0, 0, 0, 0, 1, 0);
    if (fc2mode == 0)
      reduce_ln<<<rows, 256, 0, stream>>>(Cp, sk, 1, MNa, fc2_b + d*1024, cur, 0,
                                          cur, nw, nbp, hn_bf);
    else if (fc2mode == 1)
      reduce_go(stream, Cp, sk, 1, MNa, 1024, fc2_b + d*1024, cur, 0,
                cur, nullptr, 0, 0, nullptr);
    else
      reduce_go(stream, Cp, sk, 1, MNa, 1024, fc2_b + d*1024, hbuf, 0,
                xt, nullptr, 0, 0, hard_idx);   // scatter hard rows into xt
  };

  run_block(xt, 512, 0, ln1_w + 1024, ln1_b + 1024, 0);
  run_block(xt, 512, 1, nullptr, nullptr, 1);
  gather_ln<<<256, 256, 0, stream>>>(xt, hard_idx, hbuf,
                                     ln1_w + 2*1024, ln1_b + 2*1024, hn_bf);
  run_block(hbuf, 128, 2, ln1_w + 3*1024, ln1_b + 3*1024, 0);
  run_block(hbuf, 128, 3, ln1_w + 4*1024, ln1_b + 4*1024, 0);
  run_block(hbuf, 128, 4, nullptr, nullptr, 2);
  ln_bf<<<1024, 256, 0, stream>>>(xt, ln1_w + 5*1024, ln1_b + 5*1024, hn_bf);
  run_block(xt, 512, 5, norm_w, norm_b, 0);   // fc2 reduce fused with final norm

  // ---- Phase 3: head (hn_bf = norm(xt) already) ----
  gemm_go(stream, 64, hn_bf, wt_h1, nullptr, nullptr, nullptr, nullptr, Cp, 2,
          1024, 1024, 1024, 1, 0, 0, 0, 0, 0, 1, 1);
  reduce_go(stream, Cp, 2, 1, 1024L*1024, 1024, head_b, nullptr, 0,
            nullptr, ao_bf, 0, 1, nullptr);
  gemm_go(stream, 64, ao_bf, wt_h2, nullptr, nullptr, nullptr, nullptr, Cp, 2,
          1024, 1024, 1024, 1, 0, 0, 0, 0, 0, 1, 1);
  reduce_go(stream, Cp, 2, 1, 1024L*1024, 1024, head_b + 1024, nullptr, 0,
            nullptr, hn_bf, 0, 1, nullptr);
  gemm_go(stream, 128, hn_bf, wt_ho, head_out_b, nullptr, pred, nullptr, nullptr, 1,
          1024, 4096, 1024, 1, 0, 0, 0, 0, 0, 1, 0);

  // ---- Phase 4: fused unpatchify + residual + final conv ----
  cout_fused<<<dim3(32, 64, 2), 256, 0, stream>>>(pred, r2, cout_w, cout_b, (float*)d_out);
}